// Round 17
// baseline (365.394 us; speedup 1.0000x reference)
//
#include <hip/hip_runtime.h>
#include <hip/hip_bf16.h>

#define DIM   1536
#define HEADS 12
#define HD    128
#define SEQ   4096
#define QSCALE 0.08838834764831845f
#define LOG2E 1.44269504088896f

typedef __attribute__((ext_vector_type(8))) short short8;
typedef __attribute__((ext_vector_type(4))) float f32x4;
typedef __attribute__((ext_vector_type(16))) float f32x16;

__device__ __forceinline__ unsigned short f2bf(float f) {
    __hip_bfloat16 h = __float2bfloat16(f);
    return *reinterpret_cast<unsigned short*>(&h);
}
__device__ __forceinline__ float bf2f(unsigned short u) {
    return __uint_as_float(((unsigned int)u) << 16);
}
__device__ __forceinline__ void async_cp16(void* lds, const void* g) {
    __builtin_amdgcn_global_load_lds(
        (const __attribute__((address_space(1))) unsigned int*)g,
        (__attribute__((address_space(3))) unsigned int*)lds, 16, 0, 0);
}

// ---------------------------------------------------------------------------
// f32 -> bf16 convert, 8 elements/thread. (unchanged, verified)
// ---------------------------------------------------------------------------
__global__ __launch_bounds__(256) void convert_bf16(
    const float* __restrict__ src, __hip_bfloat16* __restrict__ dst, int n8)
{
    const int i = blockIdx.x * 256 + threadIdx.x;
    if (i >= n8) return;
    const float4 a = *reinterpret_cast<const float4*>(src + (size_t)i * 8);
    const float4 b = *reinterpret_cast<const float4*>(src + (size_t)i * 8 + 4);
    uint4 o;
    o.x = (unsigned int)f2bf(a.x) | ((unsigned int)f2bf(a.y) << 16);
    o.y = (unsigned int)f2bf(a.z) | ((unsigned int)f2bf(a.w) << 16);
    o.z = (unsigned int)f2bf(b.x) | ((unsigned int)f2bf(b.y) << 16);
    o.w = (unsigned int)f2bf(b.z) | ((unsigned int)f2bf(b.w) << 16);
    *reinterpret_cast<uint4*>(dst + (size_t)i * 8) = o;
}

// ---------------------------------------------------------------------------
// GEMM (m97-style): y = A(bf16) @ W(bf16)^T + b -> bf16. (unchanged, verified)
// ---------------------------------------------------------------------------
__global__ __launch_bounds__(256) void gemm_qkv(
    const __hip_bfloat16* __restrict__ xb,
    const __hip_bfloat16* __restrict__ wqb, const float* __restrict__ bq,
    const __hip_bfloat16* __restrict__ wkb, const float* __restrict__ bk,
    const __hip_bfloat16* __restrict__ wvb, const float* __restrict__ bv,
    __hip_bfloat16* __restrict__ yq, __hip_bfloat16* __restrict__ yk,
    __hip_bfloat16* __restrict__ vrow)
{
    __shared__ __align__(16) short As[128][32];
    __shared__ __align__(16) short Bs[128][32];
    const int z  = blockIdx.z;
    const __hip_bfloat16* W = (z == 0) ? wqb : (z == 1) ? wkb : wvb;
    const float* bias = (z == 0) ? bq : (z == 1) ? bk : bv;
    __hip_bfloat16* outp = (z == 0) ? yq : (z == 1) ? yk : vrow;
    const int bm0 = blockIdx.x * 128;
    const int bn0 = blockIdx.y * 128;
    const int tid  = threadIdx.x;
    const int lane = tid & 63;
    const int wid  = tid >> 6;
    const int wm = (wid >> 1) * 64;
    const int wn = (wid & 1)  * 64;
    const int fr = lane & 15;
    const int fc = (lane >> 4) * 8;
    const int srow = tid >> 2;
    const int scol = (tid & 3) * 8;

    f32x4 acc[4][4] = {};

    for (int kt = 0; kt < DIM; kt += 32) {
        #pragma unroll
        for (int i = 0; i < 2; i++) {
            async_cp16(&As[i * 64 + ((tid >> 6) << 4)][0],
                       xb + (size_t)(bm0 + i * 64 + srow) * DIM + kt + scol);
            async_cp16(&Bs[i * 64 + ((tid >> 6) << 4)][0],
                       W + (size_t)(bn0 + i * 64 + srow) * DIM + kt + scol);
        }
        __syncthreads();
        short8 af[4], bf8[4];
        #pragma unroll
        for (int m = 0; m < 4; m++) af[m]  = *reinterpret_cast<const short8*>(&As[wm + m * 16 + fr][fc]);
        #pragma unroll
        for (int n = 0; n < 4; n++) bf8[n] = *reinterpret_cast<const short8*>(&Bs[wn + n * 16 + fr][fc]);
        #pragma unroll
        for (int m = 0; m < 4; m++)
            #pragma unroll
            for (int n = 0; n < 4; n++)
                acc[m][n] = __builtin_amdgcn_mfma_f32_16x16x32_bf16(af[m], bf8[n], acc[m][n], 0, 0, 0);
        __syncthreads();
    }

    const int crow0 = bm0 + wm + (lane >> 4) * 4;
    const int ccol0 = bn0 + wn + fr;
    #pragma unroll
    for (int n = 0; n < 4; n++) {
        const int col = ccol0 + n * 16;
        const float bb = bias[col];
        #pragma unroll
        for (int m = 0; m < 4; m++)
            #pragma unroll
            for (int r = 0; r < 4; r++)
                outp[(size_t)(crow0 + m * 16 + r) * DIM + col] =
                    __float2bfloat16(acc[m][n][r] + bb);
    }
}

// ---------------------------------------------------------------------------
// In-place RMSNorm * g + RoPE. (unchanged, verified)
// ---------------------------------------------------------------------------
__global__ __launch_bounds__(256) void rmsnorm_rope(
    __hip_bfloat16* __restrict__ yq, __hip_bfloat16* __restrict__ yk,
    const float* __restrict__ gq, const float* __restrict__ gk,
    const float* __restrict__ freqs)
{
    const int s = blockIdx.x;
    const int z = blockIdx.y;
    __hip_bfloat16* y = z ? yk : yq;
    const float* g = z ? gk : gq;
    const int t = threadIdx.x;

    float xr[3], xi[3];
    float ss = 0.f;
    #pragma unroll
    for (int i = 0; i < 3; i++) {
        const int p = t + i * 256;
        const unsigned int uu = *reinterpret_cast<const unsigned int*>(&y[(size_t)s * DIM + 2 * p]);
        xr[i] = bf2f((unsigned short)(uu & 0xffffu));
        xi[i] = bf2f((unsigned short)(uu >> 16));
        ss += xr[i] * xr[i] + xi[i] * xi[i];
    }
    #pragma unroll
    for (int m = 1; m < 64; m <<= 1) ss += __shfl_xor(ss, m, 64);
    __shared__ float red[4];
    if ((t & 63) == 0) red[t >> 6] = ss;
    __syncthreads();
    const float sum = red[0] + red[1] + red[2] + red[3];
    const float rs = rsqrtf(sum * (1.0f / DIM) + 1e-6f);
    const int f = s >> 8, hh = (s >> 4) & 15, ww = s & 15;
    const float osc = z ? 1.0f : QSCALE;
    #pragma unroll
    for (int i = 0; i < 3; i++) {
        const int p = t + i * 256;
        const int cc = p & 63;
        const int pos = (cc < 22) ? f : (cc < 43) ? hh : ww;
        const float ang = freqs[pos * 64 + cc];
        float sn, cs;
        sincosf(ang, &sn, &cs);
        const float a = xr[i] * rs * g[2 * p];
        const float b = xi[i] * rs * g[2 * p + 1];
        const unsigned int pk = (unsigned int)f2bf((a * cs - b * sn) * osc)
                              | ((unsigned int)f2bf((a * sn + b * cs) * osc) << 16);
        *reinterpret_cast<unsigned int*>(&y[(size_t)s * DIM + 2 * p]) = pk;
    }
}

// ---------------------------------------------------------------------------
// Transpose V. (unchanged, verified)
// ---------------------------------------------------------------------------
__global__ __launch_bounds__(256) void transpose_v(
    const __hip_bfloat16* __restrict__ vrow,
    __hip_bfloat16* __restrict__ vT)
{
    __shared__ __align__(16) short tile[64][72];
    const int s0 = blockIdx.x * 64;
    const int c0 = blockIdx.y * 64;
    const int t = threadIdx.x;
    #pragma unroll
    for (int i = 0; i < 2; i++) {
        const int ch = t + i * 256;
        const int r = ch >> 3, cc = (ch & 7) * 8;
        *reinterpret_cast<int4*>(&tile[r][cc]) =
            *reinterpret_cast<const int4*>(&vrow[(size_t)(s0 + r) * DIM + c0 + cc]);
    }
    __syncthreads();
    #pragma unroll
    for (int i = 0; i < 2; i++) {
        const int ch = t + i * 256;
        const int c = ch & 63, sc = (ch >> 6) * 8;
        unsigned int w0 = (unsigned short)tile[sc + 0][c] | ((unsigned int)(unsigned short)tile[sc + 1][c] << 16);
        unsigned int w1 = (unsigned short)tile[sc + 2][c] | ((unsigned int)(unsigned short)tile[sc + 3][c] << 16);
        unsigned int w2 = (unsigned short)tile[sc + 4][c] | ((unsigned int)(unsigned short)tile[sc + 5][c] << 16);
        unsigned int w3 = (unsigned short)tile[sc + 6][c] | ((unsigned int)(unsigned short)tile[sc + 7][c] << 16);
        int4 val;
        val.x = (int)w0; val.y = (int)w1; val.z = (int)w2; val.w = (int)w3;
        *reinterpret_cast<int4*>(&vT[(size_t)(c0 + c) * SEQ + s0 + sc]) = val;
    }
}

// ---------------------------------------------------------------------------
// Flash attention v9: v7 tile geometry (QBLK=128, 4 waves, 32x32x16) +
// v8 V-single-buffer schedule -> LDS 48KB -> 3 blocks/CU = 3 waves/SIMD.
// Per iter: [barA] stage V[t] + prefetch K[t+1] -> QK(K[t]) -> softmax ->
// [barB] -> PV.
// ---------------------------------------------------------------------------
__global__ __launch_bounds__(256, 3) void flash_attn(
    const __hip_bfloat16* __restrict__ qb,
    const __hip_bfloat16* __restrict__ kb,
    const __hip_bfloat16* __restrict__ vT,
    const int* __restrict__ seq_lens,
    __hip_bfloat16* __restrict__ attno)
{
    __shared__ __align__(16) short Ks[2][64][128];   // 2 x 16 KB
    __shared__ __align__(16) short Vs[128][64];      // 16 KB
    const int qt = blockIdx.x;
    const int h  = blockIdx.y;
    const int tid = threadIdx.x;
    const int lane = tid & 63;
    const int w = tid >> 6;
    const int q5 = lane & 31;
    const int hi = lane >> 5;
    const int seqlen = seq_lens[0];
    const int swz = (lane & 7) << 4;

    short8 qf[8];
    const int qrow = qt * 128 + w * 32 + q5;
    #pragma unroll
    for (int s = 0; s < 8; s++)
        qf[s] = *reinterpret_cast<const short8*>(&qb[(size_t)qrow * DIM + h * HD + s * 16 + hi * 8]);

    f32x16 oacc[4] = {};
    float m = -1e30f, l = 0.f;

    const int kROW = w * 4 + (lane >> 4);            // + i*16
    const int kCOL = ((lane & 15) ^ (kROW & 7)) * 8;
    const int vROW = w * 8 + (lane >> 3);            // + i*32
    const int vCOL = (((lane & 7) ^ (vROW & 7))) * 8;

    // prologue: stage K tile 0 into buffer 0
    #pragma unroll
    for (int i = 0; i < 4; i++)
        async_cp16(&Ks[0][i * 16 + w * 4][0],
                   kb + (size_t)(i * 16 + kROW) * DIM + h * HD + kCOL);

    for (int t = 0; t < SEQ / 64; t++) {
        const int kbase = t * 64;
        __syncthreads();   // (A) prev PV reads done; K[t] staged

        // stage V[t]; prefetch K[t+1]
        #pragma unroll
        for (int i = 0; i < 4; i++)
            async_cp16(&Vs[i * 32 + vROW][0],
                       vT + ((size_t)h * HD + i * 32 + vROW) * SEQ + kbase + vCOL);
        if (t + 1 < SEQ / 64) {
            const int nb = kbase + 64;
            #pragma unroll
            for (int i = 0; i < 4; i++)
                async_cp16(&Ks[(t + 1) & 1][i * 16 + w * 4][0],
                           kb + (size_t)(nb + i * 16 + kROW) * DIM + h * HD + kCOL);
        }

        const char* Kp = (const char*)&Ks[t & 1][0][0];

        // S^T = K Q^T : D[key 32][q 32], 2 key-blocks x 8 d-slices
        f32x16 sacc[2] = {};
        __builtin_amdgcn_s_setprio(1);
        #pragma unroll
        for (int s = 0; s < 8; s++) {
            #pragma unroll
            for (int kbk = 0; kbk < 2; kbk++) {
                short8 kf = *reinterpret_cast<const short8*>(
                    Kp + (kbk * 32 + q5) * 256 + ((s * 32 + hi * 16) ^ swz));
                sacc[kbk] = __builtin_amdgcn_mfma_f32_32x32x16_bf16(kf, qf[s], sacc[kbk], 0, 0, 0);
            }
        }
        __builtin_amdgcn_s_setprio(0);

        // row max
        float tmax = -1e30f;
        if (kbase + 64 <= seqlen) {
            #pragma unroll
            for (int kbk = 0; kbk < 2; kbk++)
                #pragma unroll
                for (int r = 0; r < 16; r++) tmax = fmaxf(tmax, sacc[kbk][r]);
        } else {
            #pragma unroll
            for (int kbk = 0; kbk < 2; kbk++) {
                #pragma unroll
                for (int r = 0; r < 16; r++) {
                    const int key = kbase + kbk * 32 + (r & 3) + 8 * (r >> 2) + 4 * hi;
                    const float sv = (key < seqlen) ? sacc[kbk][r] : -1e30f;
                    sacc[kbk][r] = sv;
                    tmax = fmaxf(tmax, sv);
                }
            }
        }
        tmax = fmaxf(tmax, __shfl_xor(tmax, 32, 64));

        // defer-max (T13)
        if (!__all(tmax <= m + 8.0f)) {
            const float mn = fmaxf(m, tmax);
            const float alpha = exp2f((m - mn) * LOG2E);
            m = mn;
            l *= alpha;
            #pragma unroll
            for (int cb = 0; cb < 4; cb++)
                #pragma unroll
                for (int r = 0; r < 16; r++) oacc[cb][r] *= alpha;
        }

        // P = exp(S - m); row sum
        float ps = 0.f;
        #pragma unroll
        for (int kbk = 0; kbk < 2; kbk++) {
            #pragma unroll
            for (int r = 0; r < 16; r++) {
                const float p = exp2f((sacc[kbk][r] - m) * LOG2E);
                sacc[kbk][r] = p;
                ps += p;
            }
        }
        ps += __shfl_xor(ps, 32, 64);
        l += ps;

        // pack P
        unsigned int W[2][4][2];
        #pragma unroll
        for (int kbk = 0; kbk < 2; kbk++)
            #pragma unroll
            for (int tq = 0; tq < 4; tq++) {
                W[kbk][tq][0] = (unsigned int)f2bf(sacc[kbk][4 * tq + 0])
                              | ((unsigned int)f2bf(sacc[kbk][4 * tq + 1]) << 16);
                W[kbk][tq][1] = (unsigned int)f2bf(sacc[kbk][4 * tq + 2])
                              | ((unsigned int)f2bf(sacc[kbk][4 * tq + 3]) << 16);
            }

        __syncthreads();   // (B) V[t] (and K[t+1]) staged

        // O^T += V^T P
        const char* Vp = (const char*)&Vs[0][0];
        #pragma unroll
        for (int ks = 0; ks < 4; ks++) {
            const int kbk = ks >> 1;
            const int te = (ks & 1) * 2, to = te + 1;
            const int a0 = (int)W[kbk][te][0], a1 = (int)W[kbk][te][1];
            const int b0 = (int)W[kbk][to][0], b1 = (int)W[kbk][to][1];
            const int xa0 = __shfl_xor(a0, 32, 64);
            const int xa1 = __shfl_xor(a1, 32, 64);
            const int xb0 = __shfl_xor(b0, 32, 64);
            const int xb1 = __shfl_xor(b1, 32, 64);
            int4 pwv;
            pwv.x = hi ? xb0 : a0;
            pwv.y = hi ? xb1 : a1;
            pwv.z = hi ? b0  : xa0;
            pwv.w = hi ? b1  : xa1;
            const short8 pf = __builtin_bit_cast(short8, pwv);
            __builtin_amdgcn_s_setprio(1);
            #pragma unroll
            for (int cb = 0; cb < 4; cb++) {
                short8 vf = *reinterpret_cast<const short8*>(
                    Vp + (cb * 32 + q5) * 128 + ((ks * 32 + hi * 16) ^ swz));
                oacc[cb] = __builtin_amdgcn_mfma_f32_32x32x16_bf16(vf, pf, oacc[cb], 0, 0, 0);
            }
            __builtin_amdgcn_s_setprio(0);
        }
    }

    // epilogue: O = O^T / l, packed 8B stores
    const float inv_l = 1.f / l;
    const size_t obase = (size_t)qrow * DIM + h * HD;
    #pragma unroll
    for (int cb = 0; cb < 4; cb++) {
        #pragma unroll
        for (int tq = 0; tq < 4; tq++) {
            uint2 pko;
            pko.x = (unsigned int)f2bf(oacc[cb][4 * tq + 0] * inv_l)
                  | ((unsigned int)f2bf(oacc[cb][4 * tq + 1] * inv_l) << 16);
            pko.y = (unsigned int)f2bf(oacc[cb][4 * tq + 2] * inv_l)
                  | ((unsigned int)f2bf(oacc[cb][4 * tq + 3] * inv_l) << 16);
            *reinterpret_cast<uint2*>(&attno[obase + cb * 32 + 8 * tq + 4 * hi]) = pko;
        }
    }
}

// ---------------------------------------------------------------------------
// Output GEMM (m97-style staging). (unchanged, verified)
// ---------------------------------------------------------------------------
__global__ __launch_bounds__(256) void gemm_out(
    const __hip_bfloat16* __restrict__ A,
    const __hip_bfloat16* __restrict__ W,
    const float* __restrict__ bias,
    float* __restrict__ outp)
{
    __shared__ __align__(16) short As[128][32];
    __shared__ __align__(16) short Bs[128][32];
    const int bm0 = blockIdx.x * 128;
    const int bn0 = blockIdx.y * 128;
    const int tid = threadIdx.x;
    const int lane = tid & 63;
    const int wid = tid >> 6;
    const int wm = (wid >> 1) * 64;
    const int wn = (wid & 1) * 64;
    const int fr = lane & 15;
    const int fc = (lane >> 4) * 8;
    const int srow = tid >> 2;
    const int scol = (tid & 3) * 8;

    f32x4 acc[4][4] = {};

    for (int kt = 0; kt < DIM; kt += 32) {
        #pragma unroll
        for (int i = 0; i < 2; i++) {
            async_cp16(&As[i * 64 + ((tid >> 6) << 4)][0],
                       A + (size_t)(bm0 + i * 64 + srow) * DIM + kt + scol);
            async_cp16(&Bs[i * 64 + ((tid >> 6) << 4)][0],
                       W + (size_t)(bn0 + i * 64 + srow) * DIM + kt + scol);
        }
        __syncthreads();
        short8 af[4], bf8[4];
        #pragma unroll
        for (int m = 0; m < 4; m++) af[m]  = *reinterpret_cast<const short8*>(&As[wm + m * 16 + fr][fc]);
        #pragma unroll
        for (int n = 0; n < 4; n++) bf8[n] = *reinterpret_cast<const short8*>(&Bs[wn + n * 16 + fr][fc]);
        #pragma unroll
        for (int m = 0; m < 4; m++)
            #pragma unroll
            for (int n = 0; n < 4; n++)
                acc[m][n] = __builtin_amdgcn_mfma_f32_16x16x32_bf16(af[m], bf8[n], acc[m][n], 0, 0, 0);
        __syncthreads();
    }

    const int crow0 = bm0 + wm + (lane >> 4) * 4;
    const int ccol0 = bn0 + wn + fr;
    #pragma unroll
    for (int n = 0; n < 4; n++) {
        const int col = ccol0 + n * 16;
        const float bb = bias[col];
        #pragma unroll
        for (int m = 0; m < 4; m++)
            #pragma unroll
            for (int r = 0; r < 4; r++)
                outp[(size_t)(crow0 + m * 16 + r) * DIM + col] = acc[m][n][r] + bb;
    }
}

// ---------------------------------------------------------------------------
extern "C" void kernel_launch(void* const* d_in, const int* in_sizes, int n_in,
                              void* d_out, int out_size, void* d_ws, size_t ws_size,
                              hipStream_t stream)
{
    const float* x        = (const float*)d_in[0];
    const int*   seq_lens = (const int*)d_in[1];
    const float* freqs    = (const float*)d_in[3];
    const float* wq = (const float*)d_in[4];
    const float* bq = (const float*)d_in[5];
    const float* wk = (const float*)d_in[6];
    const float* bk = (const float*)d_in[7];
    const float* wv = (const float*)d_in[8];
    const float* bv = (const float*)d_in[9];
    const float* wo = (const float*)d_in[10];
    const float* bo = (const float*)d_in[11];
    const float* gq = (const float*)d_in[12];
    const float* gk = (const float*)d_in[13];
    float* out = (float*)d_out;

    // workspace (50,331,648 bytes) + d_out used as early scratch:
    //   yq bf16 [0, 12582912)          (q; dead after flash -> wob aliases)
    //   yk bf16 [12582912, 25165824)
    //   vrow bf16 [25165824, 37748736) (dead after transpose_v; attno aliases)
    //   vT bf16 [37748736, 50331648)   (xb lives here until transpose_v)
    //   wq/wk/wv bf16 -> d_out scratch (until gemm_out writes)
    char* ws = (char*)d_ws;
    __hip_bfloat16* yq    = (__hip_bfloat16*)(ws);
    __hip_bfloat16* yk    = (__hip_bfloat16*)(ws + 12582912);
    __hip_bfloat16* vrow  = (__hip_bfloat16*)(ws + 25165824);
    __hip_bfloat16* vT    = (__hip_bfloat16*)(ws + 37748736);
    __hip_bfloat16* attno = (__hip_bfloat16*)(ws + 25165824);
    __hip_bfloat16* xb    = (__hip_bfloat16*)(ws + 37748736);
    __hip_bfloat16* wob   = (__hip_bfloat16*)(ws);
    __hip_bfloat16* wqb   = (__hip_bfloat16*)d_out;
    __hip_bfloat16* wkb   = wqb + 2359296;
    __hip_bfloat16* wvb   = wkb + 2359296;

    dim3 blk(256);
    convert_bf16<<<dim3(3072), blk, 0, stream>>>(x,  xb,  786432);
    convert_bf16<<<dim3(1152), blk, 0, stream>>>(wq, wqb, 294912);
    convert_bf16<<<dim3(1152), blk, 0, stream>>>(wk, wkb, 294912);
    convert_bf16<<<dim3(1152), blk, 0, stream>>>(wv, wvb, 294912);
    gemm_qkv    <<<dim3(32, 12, 3), blk, 0, stream>>>(xb, wqb, bq, wkb, bk, wvb, bv, yq, yk, vrow);
    rmsnorm_rope<<<dim3(4096, 2),   blk, 0, stream>>>(yq, yk, gq, gk, freqs);
    transpose_v <<<dim3(64, 24),    blk, 0, stream>>>(vrow, vT);
    flash_attn  <<<dim3(32, 12),    blk, 0, stream>>>(yq, yk, vT, seq_lens, attno);
    convert_bf16<<<dim3(1152), blk, 0, stream>>>(wo, wob, 294912);
    gemm_out    <<<dim3(32, 12),    blk, 0, stream>>>(attno, wob, bo, out);
}

// Round 18
// 330.070 us; speedup vs baseline: 1.1070x; 1.1070x over previous
//
#include <hip/hip_runtime.h>
#include <hip/hip_bf16.h>

#define DIM   1536
#define HEADS 12
#define HD    128
#define SEQ   4096
#define QSCALE 0.08838834764831845f
#define LOG2E 1.44269504088896f

typedef __attribute__((ext_vector_type(8))) short short8;
typedef __attribute__((ext_vector_type(4))) float f32x4;
typedef __attribute__((ext_vector_type(16))) float f32x16;

__device__ __forceinline__ unsigned short f2bf(float f) {
    __hip_bfloat16 h = __float2bfloat16(f);
    return *reinterpret_cast<unsigned short*>(&h);
}
__device__ __forceinline__ float bf2f(unsigned short u) {
    return __uint_as_float(((unsigned int)u) << 16);
}
__device__ __forceinline__ void async_cp16(void* lds, const void* g) {
    __builtin_amdgcn_global_load_lds(
        (const __attribute__((address_space(1))) unsigned int*)g,
        (__attribute__((address_space(3))) unsigned int*)lds, 16, 0, 0);
}

// ---------------------------------------------------------------------------
// f32 -> bf16 convert, 8 elements/thread. (unchanged, verified)
// ---------------------------------------------------------------------------
__global__ __launch_bounds__(256) void convert_bf16(
    const float* __restrict__ src, __hip_bfloat16* __restrict__ dst, int n8)
{
    const int i = blockIdx.x * 256 + threadIdx.x;
    if (i >= n8) return;
    const float4 a = *reinterpret_cast<const float4*>(src + (size_t)i * 8);
    const float4 b = *reinterpret_cast<const float4*>(src + (size_t)i * 8 + 4);
    uint4 o;
    o.x = (unsigned int)f2bf(a.x) | ((unsigned int)f2bf(a.y) << 16);
    o.y = (unsigned int)f2bf(a.z) | ((unsigned int)f2bf(a.w) << 16);
    o.z = (unsigned int)f2bf(b.x) | ((unsigned int)f2bf(b.y) << 16);
    o.w = (unsigned int)f2bf(b.z) | ((unsigned int)f2bf(b.w) << 16);
    *reinterpret_cast<uint4*>(dst + (size_t)i * 8) = o;
}

// ---------------------------------------------------------------------------
// GEMM (m97-style): y = A(bf16) @ W(bf16)^T + b -> bf16. (unchanged, verified)
// ---------------------------------------------------------------------------
__global__ __launch_bounds__(256) void gemm_qkv(
    const __hip_bfloat16* __restrict__ xb,
    const __hip_bfloat16* __restrict__ wqb, const float* __restrict__ bq,
    const __hip_bfloat16* __restrict__ wkb, const float* __restrict__ bk,
    const __hip_bfloat16* __restrict__ wvb, const float* __restrict__ bv,
    __hip_bfloat16* __restrict__ yq, __hip_bfloat16* __restrict__ yk,
    __hip_bfloat16* __restrict__ vrow)
{
    __shared__ __align__(16) short As[128][32];
    __shared__ __align__(16) short Bs[128][32];
    const int z  = blockIdx.z;
    const __hip_bfloat16* W = (z == 0) ? wqb : (z == 1) ? wkb : wvb;
    const float* bias = (z == 0) ? bq : (z == 1) ? bk : bv;
    __hip_bfloat16* outp = (z == 0) ? yq : (z == 1) ? yk : vrow;
    const int bm0 = blockIdx.x * 128;
    const int bn0 = blockIdx.y * 128;
    const int tid  = threadIdx.x;
    const int lane = tid & 63;
    const int wid  = tid >> 6;
    const int wm = (wid >> 1) * 64;
    const int wn = (wid & 1)  * 64;
    const int fr = lane & 15;
    const int fc = (lane >> 4) * 8;
    const int srow = tid >> 2;
    const int scol = (tid & 3) * 8;

    f32x4 acc[4][4] = {};

    for (int kt = 0; kt < DIM; kt += 32) {
        #pragma unroll
        for (int i = 0; i < 2; i++) {
            async_cp16(&As[i * 64 + ((tid >> 6) << 4)][0],
                       xb + (size_t)(bm0 + i * 64 + srow) * DIM + kt + scol);
            async_cp16(&Bs[i * 64 + ((tid >> 6) << 4)][0],
                       W + (size_t)(bn0 + i * 64 + srow) * DIM + kt + scol);
        }
        __syncthreads();
        short8 af[4], bf8[4];
        #pragma unroll
        for (int m = 0; m < 4; m++) af[m]  = *reinterpret_cast<const short8*>(&As[wm + m * 16 + fr][fc]);
        #pragma unroll
        for (int n = 0; n < 4; n++) bf8[n] = *reinterpret_cast<const short8*>(&Bs[wn + n * 16 + fr][fc]);
        #pragma unroll
        for (int m = 0; m < 4; m++)
            #pragma unroll
            for (int n = 0; n < 4; n++)
                acc[m][n] = __builtin_amdgcn_mfma_f32_16x16x32_bf16(af[m], bf8[n], acc[m][n], 0, 0, 0);
        __syncthreads();
    }

    const int crow0 = bm0 + wm + (lane >> 4) * 4;
    const int ccol0 = bn0 + wn + fr;
    #pragma unroll
    for (int n = 0; n < 4; n++) {
        const int col = ccol0 + n * 16;
        const float bb = bias[col];
        #pragma unroll
        for (int m = 0; m < 4; m++)
            #pragma unroll
            for (int r = 0; r < 4; r++)
                outp[(size_t)(crow0 + m * 16 + r) * DIM + col] =
                    __float2bfloat16(acc[m][n][r] + bb);
    }
}

// ---------------------------------------------------------------------------
// In-place RMSNorm * g + RoPE. (unchanged, verified)
// ---------------------------------------------------------------------------
__global__ __launch_bounds__(256) void rmsnorm_rope(
    __hip_bfloat16* __restrict__ yq, __hip_bfloat16* __restrict__ yk,
    const float* __restrict__ gq, const float* __restrict__ gk,
    const float* __restrict__ freqs)
{
    const int s = blockIdx.x;
    const int z = blockIdx.y;
    __hip_bfloat16* y = z ? yk : yq;
    const float* g = z ? gk : gq;
    const int t = threadIdx.x;

    float xr[3], xi[3];
    float ss = 0.f;
    #pragma unroll
    for (int i = 0; i < 3; i++) {
        const int p = t + i * 256;
        const unsigned int uu = *reinterpret_cast<const unsigned int*>(&y[(size_t)s * DIM + 2 * p]);
        xr[i] = bf2f((unsigned short)(uu & 0xffffu));
        xi[i] = bf2f((unsigned short)(uu >> 16));
        ss += xr[i] * xr[i] + xi[i] * xi[i];
    }
    #pragma unroll
    for (int m = 1; m < 64; m <<= 1) ss += __shfl_xor(ss, m, 64);
    __shared__ float red[4];
    if ((t & 63) == 0) red[t >> 6] = ss;
    __syncthreads();
    const float sum = red[0] + red[1] + red[2] + red[3];
    const float rs = rsqrtf(sum * (1.0f / DIM) + 1e-6f);
    const int f = s >> 8, hh = (s >> 4) & 15, ww = s & 15;
    const float osc = z ? 1.0f : QSCALE;
    #pragma unroll
    for (int i = 0; i < 3; i++) {
        const int p = t + i * 256;
        const int cc = p & 63;
        const int pos = (cc < 22) ? f : (cc < 43) ? hh : ww;
        const float ang = freqs[pos * 64 + cc];
        float sn, cs;
        sincosf(ang, &sn, &cs);
        const float a = xr[i] * rs * g[2 * p];
        const float b = xi[i] * rs * g[2 * p + 1];
        const unsigned int pk = (unsigned int)f2bf((a * cs - b * sn) * osc)
                              | ((unsigned int)f2bf((a * sn + b * cs) * osc) << 16);
        *reinterpret_cast<unsigned int*>(&y[(size_t)s * DIM + 2 * p]) = pk;
    }
}

// ---------------------------------------------------------------------------
// Transpose V. (unchanged, verified)
// ---------------------------------------------------------------------------
__global__ __launch_bounds__(256) void transpose_v(
    const __hip_bfloat16* __restrict__ vrow,
    __hip_bfloat16* __restrict__ vT)
{
    __shared__ __align__(16) short tile[64][72];
    const int s0 = blockIdx.x * 64;
    const int c0 = blockIdx.y * 64;
    const int t = threadIdx.x;
    #pragma unroll
    for (int i = 0; i < 2; i++) {
        const int ch = t + i * 256;
        const int r = ch >> 3, cc = (ch & 7) * 8;
        *reinterpret_cast<int4*>(&tile[r][cc]) =
            *reinterpret_cast<const int4*>(&vrow[(size_t)(s0 + r) * DIM + c0 + cc]);
    }
    __syncthreads();
    #pragma unroll
    for (int i = 0; i < 2; i++) {
        const int ch = t + i * 256;
        const int c = ch & 63, sc = (ch >> 6) * 8;
        unsigned int w0 = (unsigned short)tile[sc + 0][c] | ((unsigned int)(unsigned short)tile[sc + 1][c] << 16);
        unsigned int w1 = (unsigned short)tile[sc + 2][c] | ((unsigned int)(unsigned short)tile[sc + 3][c] << 16);
        unsigned int w2 = (unsigned short)tile[sc + 4][c] | ((unsigned int)(unsigned short)tile[sc + 5][c] << 16);
        unsigned int w3 = (unsigned short)tile[sc + 6][c] | ((unsigned int)(unsigned short)tile[sc + 7][c] << 16);
        int4 val;
        val.x = (int)w0; val.y = (int)w1; val.z = (int)w2; val.w = (int)w3;
        *reinterpret_cast<int4*>(&vT[(size_t)(c0 + c) * SEQ + s0 + sc]) = val;
    }
}

// ---------------------------------------------------------------------------
// Flash attention v10: v7 geometry (QBLK=128, 4 waves, 32x32x16) + T15
// deferred-PV pipeline: iter t does QK[t] and PV[t-1] back-to-back (both
// MFMA, independent), softmax[t] VALU overlaps the MFMA drain.
// K double-buffered, V TRIPLE-buffered (80KB LDS, 2 blocks/CU).
// P[t-1] kept packed in regs (Wp, unconditionally written each iter).
// ---------------------------------------------------------------------------
__global__ __launch_bounds__(256, 2) void flash_attn(
    const __hip_bfloat16* __restrict__ qb,
    const __hip_bfloat16* __restrict__ kb,
    const __hip_bfloat16* __restrict__ vT,
    const int* __restrict__ seq_lens,
    __hip_bfloat16* __restrict__ attno)
{
    __shared__ __align__(16) short Ks[2][64][128];   // 32 KB
    __shared__ __align__(16) short Vs[3][128][64];   // 48 KB
    const int qt = blockIdx.x;
    const int h  = blockIdx.y;
    const int tid = threadIdx.x;
    const int lane = tid & 63;
    const int w = tid >> 6;
    const int q5 = lane & 31;
    const int hi = lane >> 5;
    const int seqlen = seq_lens[0];
    const int swz = (lane & 7) << 4;
    const int NT = SEQ / 64;

    short8 qf[8];
    const int qrow = qt * 128 + w * 32 + q5;
    #pragma unroll
    for (int s = 0; s < 8; s++)
        qf[s] = *reinterpret_cast<const short8*>(&qb[(size_t)qrow * DIM + h * HD + s * 16 + hi * 8]);

    f32x16 oacc[4] = {};
    float m = -1e30f, l = 0.f;
    unsigned int Wp[2][4][2];    // packed P of previous tile (scale m[t-1])

    const int kROW = w * 4 + (lane >> 4);
    const int kCOL = ((lane & 15) ^ (kROW & 7)) * 8;
    const int vROW = w * 8 + (lane >> 3);
    const int vCOL = (((lane & 7) ^ (vROW & 7))) * 8;

    // stage tile 0 (K->buf0, V->slot0)
    #pragma unroll
    for (int i = 0; i < 4; i++) {
        async_cp16(&Ks[0][i * 16 + w * 4][0],
                   kb + (size_t)(i * 16 + kROW) * DIM + h * HD + kCOL);
        async_cp16(&Vs[0][i * 32 + vROW][0],
                   vT + ((size_t)h * HD + i * 32 + vROW) * SEQ + vCOL);
    }
    __syncthreads();

    // ---- peeled iter 0: stage tile1, QK[0], softmax[0] -> Wp (no PV) ----
    {
        #pragma unroll
        for (int i = 0; i < 4; i++) {
            async_cp16(&Ks[1][i * 16 + w * 4][0],
                       kb + (size_t)(64 + i * 16 + kROW) * DIM + h * HD + kCOL);
            async_cp16(&Vs[1][i * 32 + vROW][0],
                       vT + ((size_t)h * HD + i * 32 + vROW) * SEQ + 64 + vCOL);
        }
        const char* Kp = (const char*)&Ks[0][0][0];
        f32x16 sacc[2] = {};
        __builtin_amdgcn_s_setprio(1);
        #pragma unroll
        for (int s = 0; s < 8; s++)
            #pragma unroll
            for (int kbk = 0; kbk < 2; kbk++) {
                short8 kf = *reinterpret_cast<const short8*>(
                    Kp + (kbk * 32 + q5) * 256 + ((s * 32 + hi * 16) ^ swz));
                sacc[kbk] = __builtin_amdgcn_mfma_f32_32x32x16_bf16(kf, qf[s], sacc[kbk], 0, 0, 0);
            }
        __builtin_amdgcn_s_setprio(0);
        float tmax = -1e30f;
        #pragma unroll
        for (int kbk = 0; kbk < 2; kbk++)
            #pragma unroll
            for (int r = 0; r < 16; r++) {
                const int key = kbk * 32 + (r & 3) + 8 * (r >> 2) + 4 * hi;
                const float sv = (key < seqlen) ? sacc[kbk][r] : -1e30f;
                sacc[kbk][r] = sv;
                tmax = fmaxf(tmax, sv);
            }
        tmax = fmaxf(tmax, __shfl_xor(tmax, 32, 64));
        const float mn = fmaxf(m, tmax);
        m = mn;
        float ps = 0.f;
        #pragma unroll
        for (int kbk = 0; kbk < 2; kbk++)
            #pragma unroll
            for (int r = 0; r < 16; r++) {
                const float p = exp2f((sacc[kbk][r] - m) * LOG2E);
                sacc[kbk][r] = p;
                ps += p;
            }
        ps += __shfl_xor(ps, 32, 64);
        l = ps;
        #pragma unroll
        for (int kbk = 0; kbk < 2; kbk++)
            #pragma unroll
            for (int tq = 0; tq < 4; tq++) {
                Wp[kbk][tq][0] = (unsigned int)f2bf(sacc[kbk][4 * tq + 0])
                               | ((unsigned int)f2bf(sacc[kbk][4 * tq + 1]) << 16);
                Wp[kbk][tq][1] = (unsigned int)f2bf(sacc[kbk][4 * tq + 2])
                               | ((unsigned int)f2bf(sacc[kbk][4 * tq + 3]) << 16);
            }
    }

    // ---- main pipeline: t = 1..NT-1 ----
    int vprev = 0, vnext = 2;
    for (int t = 1; t < NT; t++) {
        const int kbase = t * 64;
        __syncthreads();   // stage[t] done; all waves finished iter t-1

        if (t + 1 < NT) {
            const int nb = kbase + 64;
            #pragma unroll
            for (int i = 0; i < 4; i++) {
                async_cp16(&Ks[(t + 1) & 1][i * 16 + w * 4][0],
                           kb + (size_t)(nb + i * 16 + kROW) * DIM + h * HD + kCOL);
                async_cp16(&Vs[vnext][i * 32 + vROW][0],
                           vT + ((size_t)h * HD + i * 32 + vROW) * SEQ + nb + vCOL);
            }
        }

        // QK[t] (MFMA cluster 1)
        const char* Kp = (const char*)&Ks[t & 1][0][0];
        f32x16 sacc[2] = {};
        __builtin_amdgcn_s_setprio(1);
        #pragma unroll
        for (int s = 0; s < 8; s++)
            #pragma unroll
            for (int kbk = 0; kbk < 2; kbk++) {
                short8 kf = *reinterpret_cast<const short8*>(
                    Kp + (kbk * 32 + q5) * 256 + ((s * 32 + hi * 16) ^ swz));
                sacc[kbk] = __builtin_amdgcn_mfma_f32_32x32x16_bf16(kf, qf[s], sacc[kbk], 0, 0, 0);
            }
        __builtin_amdgcn_s_setprio(0);

        // PV[t-1] (MFMA cluster 2; independent of sacc)
        {
            const char* Vp = (const char*)&Vs[vprev][0][0];
            #pragma unroll
            for (int ks = 0; ks < 4; ks++) {
                const int kbk = ks >> 1;
                const int te = (ks & 1) * 2, to = te + 1;
                const int a0 = (int)Wp[kbk][te][0], a1 = (int)Wp[kbk][te][1];
                const int b0 = (int)Wp[kbk][to][0], b1 = (int)Wp[kbk][to][1];
                const int xa0 = __shfl_xor(a0, 32, 64);
                const int xa1 = __shfl_xor(a1, 32, 64);
                const int xb0 = __shfl_xor(b0, 32, 64);
                const int xb1 = __shfl_xor(b1, 32, 64);
                int4 pwv;
                pwv.x = hi ? xb0 : a0;
                pwv.y = hi ? xb1 : a1;
                pwv.z = hi ? b0  : xa0;
                pwv.w = hi ? b1  : xa1;
                const short8 pf = __builtin_bit_cast(short8, pwv);
                __builtin_amdgcn_s_setprio(1);
                #pragma unroll
                for (int cb = 0; cb < 4; cb++) {
                    short8 vf = *reinterpret_cast<const short8*>(
                        Vp + (cb * 32 + q5) * 128 + ((ks * 32 + hi * 16) ^ swz));
                    oacc[cb] = __builtin_amdgcn_mfma_f32_32x32x16_bf16(vf, pf, oacc[cb], 0, 0, 0);
                }
                __builtin_amdgcn_s_setprio(0);
            }
        }

        // softmax[t] (VALU; overlaps MFMA drain)
        float tmax = -1e30f;
        if (kbase + 64 <= seqlen) {
            #pragma unroll
            for (int kbk = 0; kbk < 2; kbk++)
                #pragma unroll
                for (int r = 0; r < 16; r++) tmax = fmaxf(tmax, sacc[kbk][r]);
        } else {
            #pragma unroll
            for (int kbk = 0; kbk < 2; kbk++)
                #pragma unroll
                for (int r = 0; r < 16; r++) {
                    const int key = kbase + kbk * 32 + (r & 3) + 8 * (r >> 2) + 4 * hi;
                    const float sv = (key < seqlen) ? sacc[kbk][r] : -1e30f;
                    sacc[kbk][r] = sv;
                    tmax = fmaxf(tmax, sv);
                }
        }
        tmax = fmaxf(tmax, __shfl_xor(tmax, 32, 64));
        if (!__all(tmax <= m + 8.0f)) {
            const float mn = fmaxf(m, tmax);
            const float alpha = exp2f((m - mn) * LOG2E);
            m = mn;
            l *= alpha;
            #pragma unroll
            for (int cb = 0; cb < 4; cb++)
                #pragma unroll
                for (int r = 0; r < 16; r++) oacc[cb][r] *= alpha;
        }
        float ps = 0.f;
        #pragma unroll
        for (int kbk = 0; kbk < 2; kbk++)
            #pragma unroll
            for (int r = 0; r < 16; r++) {
                const float p = exp2f((sacc[kbk][r] - m) * LOG2E);
                sacc[kbk][r] = p;
                ps += p;
            }
        ps += __shfl_xor(ps, 32, 64);
        l += ps;
        #pragma unroll
        for (int kbk = 0; kbk < 2; kbk++)
            #pragma unroll
            for (int tq = 0; tq < 4; tq++) {
                Wp[kbk][tq][0] = (unsigned int)f2bf(sacc[kbk][4 * tq + 0])
                               | ((unsigned int)f2bf(sacc[kbk][4 * tq + 1]) << 16);
                Wp[kbk][tq][1] = (unsigned int)f2bf(sacc[kbk][4 * tq + 2])
                               | ((unsigned int)f2bf(sacc[kbk][4 * tq + 3]) << 16);
            }

        vprev = (vprev == 2) ? 0 : vprev + 1;
        vnext = (vnext == 2) ? 0 : vnext + 1;
    }

    // ---- epilogue: PV[NT-1] (V slot = vprev), then divide + store ----
    {
        const char* Vp = (const char*)&Vs[vprev][0][0];
        #pragma unroll
        for (int ks = 0; ks < 4; ks++) {
            const int kbk = ks >> 1;
            const int te = (ks & 1) * 2, to = te + 1;
            const int a0 = (int)Wp[kbk][te][0], a1 = (int)Wp[kbk][te][1];
            const int b0 = (int)Wp[kbk][to][0], b1 = (int)Wp[kbk][to][1];
            const int xa0 = __shfl_xor(a0, 32, 64);
            const int xa1 = __shfl_xor(a1, 32, 64);
            const int xb0 = __shfl_xor(b0, 32, 64);
            const int xb1 = __shfl_xor(b1, 32, 64);
            int4 pwv;
            pwv.x = hi ? xb0 : a0;
            pwv.y = hi ? xb1 : a1;
            pwv.z = hi ? b0  : xa0;
            pwv.w = hi ? b1  : xa1;
            const short8 pf = __builtin_bit_cast(short8, pwv);
            #pragma unroll
            for (int cb = 0; cb < 4; cb++) {
                short8 vf = *reinterpret_cast<const short8*>(
                    Vp + (cb * 32 + q5) * 128 + ((ks * 32 + hi * 16) ^ swz));
                oacc[cb] = __builtin_amdgcn_mfma_f32_32x32x16_bf16(vf, pf, oacc[cb], 0, 0, 0);
            }
        }
    }

    const float inv_l = 1.f / l;
    const size_t obase = (size_t)qrow * DIM + h * HD;
    #pragma unroll
    for (int cb = 0; cb < 4; cb++) {
        #pragma unroll
        for (int tq = 0; tq < 4; tq++) {
            uint2 pko;
            pko.x = (unsigned int)f2bf(oacc[cb][4 * tq + 0] * inv_l)
                  | ((unsigned int)f2bf(oacc[cb][4 * tq + 1] * inv_l) << 16);
            pko.y = (unsigned int)f2bf(oacc[cb][4 * tq + 2] * inv_l)
                  | ((unsigned int)f2bf(oacc[cb][4 * tq + 3] * inv_l) << 16);
            *reinterpret_cast<uint2*>(&attno[obase + cb * 32 + 8 * tq + 4 * hi]) = pko;
        }
    }
}

// ---------------------------------------------------------------------------
// Output GEMM (m97-style staging). (unchanged, verified)
// ---------------------------------------------------------------------------
__global__ __launch_bounds__(256) void gemm_out(
    const __hip_bfloat16* __restrict__ A,
    const __hip_bfloat16* __restrict__ W,
    const float* __restrict__ bias,
    float* __restrict__ outp)
{
    __shared__ __align__(16) short As[128][32];
    __shared__ __align__(16) short Bs[128][32];
    const int bm0 = blockIdx.x * 128;
    const int bn0 = blockIdx.y * 128;
    const int tid = threadIdx.x;
    const int lane = tid & 63;
    const int wid = tid >> 6;
    const int wm = (wid >> 1) * 64;
    const int wn = (wid & 1) * 64;
    const int fr = lane & 15;
    const int fc = (lane >> 4) * 8;
    const int srow = tid >> 2;
    const int scol = (tid & 3) * 8;

    f32x4 acc[4][4] = {};

    for (int kt = 0; kt < DIM; kt += 32) {
        #pragma unroll
        for (int i = 0; i < 2; i++) {
            async_cp16(&As[i * 64 + ((tid >> 6) << 4)][0],
                       A + (size_t)(bm0 + i * 64 + srow) * DIM + kt + scol);
            async_cp16(&Bs[i * 64 + ((tid >> 6) << 4)][0],
                       W + (size_t)(bn0 + i * 64 + srow) * DIM + kt + scol);
        }
        __syncthreads();
        short8 af[4], bf8[4];
        #pragma unroll
        for (int m = 0; m < 4; m++) af[m]  = *reinterpret_cast<const short8*>(&As[wm + m * 16 + fr][fc]);
        #pragma unroll
        for (int n = 0; n < 4; n++) bf8[n] = *reinterpret_cast<const short8*>(&Bs[wn + n * 16 + fr][fc]);
        #pragma unroll
        for (int m = 0; m < 4; m++)
            #pragma unroll
            for (int n = 0; n < 4; n++)
                acc[m][n] = __builtin_amdgcn_mfma_f32_16x16x32_bf16(af[m], bf8[n], acc[m][n], 0, 0, 0);
        __syncthreads();
    }

    const int crow0 = bm0 + wm + (lane >> 4) * 4;
    const int ccol0 = bn0 + wn + fr;
    #pragma unroll
    for (int n = 0; n < 4; n++) {
        const int col = ccol0 + n * 16;
        const float bb = bias[col];
        #pragma unroll
        for (int m = 0; m < 4; m++)
            #pragma unroll
            for (int r = 0; r < 4; r++)
                outp[(size_t)(crow0 + m * 16 + r) * DIM + col] = acc[m][n][r] + bb;
    }
}

// ---------------------------------------------------------------------------
extern "C" void kernel_launch(void* const* d_in, const int* in_sizes, int n_in,
                              void* d_out, int out_size, void* d_ws, size_t ws_size,
                              hipStream_t stream)
{
    const float* x        = (const float*)d_in[0];
    const int*   seq_lens = (const int*)d_in[1];
    const float* freqs    = (const float*)d_in[3];
    const float* wq = (const float*)d_in[4];
    const float* bq = (const float*)d_in[5];
    const float* wk = (const float*)d_in[6];
    const float* bk = (const float*)d_in[7];
    const float* wv = (const float*)d_in[8];
    const float* bv = (const float*)d_in[9];
    const float* wo = (const float*)d_in[10];
    const float* bo = (const float*)d_in[11];
    const float* gq = (const float*)d_in[12];
    const float* gk = (const float*)d_in[13];
    float* out = (float*)d_out;

    // workspace (50,331,648 bytes) + d_out used as early scratch:
    //   yq bf16 [0, 12582912)          (q; dead after flash -> wob aliases)
    //   yk bf16 [12582912, 25165824)
    //   vrow bf16 [25165824, 37748736) (dead after transpose_v; attno aliases)
    //   vT bf16 [37748736, 50331648)   (xb lives here until transpose_v)
    //   wq/wk/wv bf16 -> d_out scratch (until gemm_out writes)
    char* ws = (char*)d_ws;
    __hip_bfloat16* yq    = (__hip_bfloat16*)(ws);
    __hip_bfloat16* yk    = (__hip_bfloat16*)(ws + 12582912);
    __hip_bfloat16* vrow  = (__hip_bfloat16*)(ws + 25165824);
    __hip_bfloat16* vT    = (__hip_bfloat16*)(ws + 37748736);
    __hip_bfloat16* attno = (__hip_bfloat16*)(ws + 25165824);
    __hip_bfloat16* xb    = (__hip_bfloat16*)(ws + 37748736);
    __hip_bfloat16* wob   = (__hip_bfloat16*)(ws);
    __hip_bfloat16* wqb   = (__hip_bfloat16*)d_out;
    __hip_bfloat16* wkb   = wqb + 2359296;
    __hip_bfloat16* wvb   = wkb + 2359296;

    dim3 blk(256);
    convert_bf16<<<dim3(3072), blk, 0, stream>>>(x,  xb,  786432);
    convert_bf16<<<dim3(1152), blk, 0, stream>>>(wq, wqb, 294912);
    convert_bf16<<<dim3(1152), blk, 0, stream>>>(wk, wkb, 294912);
    convert_bf16<<<dim3(1152), blk, 0, stream>>>(wv, wvb, 294912);
    gemm_qkv    <<<dim3(32, 12, 3), blk, 0, stream>>>(xb, wqb, bq, wkb, bk, wvb, bv, yq, yk, vrow);
    rmsnorm_rope<<<dim3(4096, 2),   blk, 0, stream>>>(yq, yk, gq, gk, freqs);
    transpose_v <<<dim3(64, 24),    blk, 0, stream>>>(vrow, vT);
    flash_attn  <<<dim3(32, 12),    blk, 0, stream>>>(yq, yk, vT, seq_lens, attno);
    convert_bf16<<<dim3(1152), blk, 0, stream>>>(wo, wob, 294912);
    gemm_out    <<<dim3(32, 12),    blk, 0, stream>>>(attno, wob, bo, out);
}

// Round 19
// 328.867 us; speedup vs baseline: 1.1111x; 1.0037x over previous
//
#include <hip/hip_runtime.h>
#include <hip/hip_bf16.h>

#define DIM   1536
#define HEADS 12
#define HD    128
#define SEQ   4096
#define QSCALE 0.08838834764831845f
#define LOG2E 1.44269504088896f

typedef __attribute__((ext_vector_type(8))) short short8;
typedef __attribute__((ext_vector_type(4))) float f32x4;
typedef __attribute__((ext_vector_type(16))) float f32x16;

__device__ __forceinline__ unsigned short f2bf(float f) {
    __hip_bfloat16 h = __float2bfloat16(f);
    return *reinterpret_cast<unsigned short*>(&h);
}
__device__ __forceinline__ float bf2f(unsigned short u) {
    return __uint_as_float(((unsigned int)u) << 16);
}
__device__ __forceinline__ void async_cp16(void* lds, const void* g) {
    __builtin_amdgcn_global_load_lds(
        (const __attribute__((address_space(1))) unsigned int*)g,
        (__attribute__((address_space(3))) unsigned int*)lds, 16, 0, 0);
}

// ---------------------------------------------------------------------------
// f32 -> bf16 convert, 8 elements/thread. (unchanged, verified)
// ---------------------------------------------------------------------------
__global__ __launch_bounds__(256) void convert_bf16(
    const float* __restrict__ src, __hip_bfloat16* __restrict__ dst, int n8)
{
    const int i = blockIdx.x * 256 + threadIdx.x;
    if (i >= n8) return;
    const float4 a = *reinterpret_cast<const float4*>(src + (size_t)i * 8);
    const float4 b = *reinterpret_cast<const float4*>(src + (size_t)i * 8 + 4);
    uint4 o;
    o.x = (unsigned int)f2bf(a.x) | ((unsigned int)f2bf(a.y) << 16);
    o.y = (unsigned int)f2bf(a.z) | ((unsigned int)f2bf(a.w) << 16);
    o.z = (unsigned int)f2bf(b.x) | ((unsigned int)f2bf(b.y) << 16);
    o.w = (unsigned int)f2bf(b.z) | ((unsigned int)f2bf(b.w) << 16);
    *reinterpret_cast<uint4*>(dst + (size_t)i * 8) = o;
}

// ---------------------------------------------------------------------------
// GEMM (m97-style): y = A(bf16) @ W(bf16)^T + b -> bf16. (unchanged, verified)
// ---------------------------------------------------------------------------
__global__ __launch_bounds__(256) void gemm_qkv(
    const __hip_bfloat16* __restrict__ xb,
    const __hip_bfloat16* __restrict__ wqb, const float* __restrict__ bq,
    const __hip_bfloat16* __restrict__ wkb, const float* __restrict__ bk,
    const __hip_bfloat16* __restrict__ wvb, const float* __restrict__ bv,
    __hip_bfloat16* __restrict__ yq, __hip_bfloat16* __restrict__ yk,
    __hip_bfloat16* __restrict__ vrow)
{
    __shared__ __align__(16) short As[128][32];
    __shared__ __align__(16) short Bs[128][32];
    const int z  = blockIdx.z;
    const __hip_bfloat16* W = (z == 0) ? wqb : (z == 1) ? wkb : wvb;
    const float* bias = (z == 0) ? bq : (z == 1) ? bk : bv;
    __hip_bfloat16* outp = (z == 0) ? yq : (z == 1) ? yk : vrow;
    const int bm0 = blockIdx.x * 128;
    const int bn0 = blockIdx.y * 128;
    const int tid  = threadIdx.x;
    const int lane = tid & 63;
    const int wid  = tid >> 6;
    const int wm = (wid >> 1) * 64;
    const int wn = (wid & 1)  * 64;
    const int fr = lane & 15;
    const int fc = (lane >> 4) * 8;
    const int srow = tid >> 2;
    const int scol = (tid & 3) * 8;

    f32x4 acc[4][4] = {};

    for (int kt = 0; kt < DIM; kt += 32) {
        #pragma unroll
        for (int i = 0; i < 2; i++) {
            async_cp16(&As[i * 64 + ((tid >> 6) << 4)][0],
                       xb + (size_t)(bm0 + i * 64 + srow) * DIM + kt + scol);
            async_cp16(&Bs[i * 64 + ((tid >> 6) << 4)][0],
                       W + (size_t)(bn0 + i * 64 + srow) * DIM + kt + scol);
        }
        __syncthreads();
        short8 af[4], bf8[4];
        #pragma unroll
        for (int m = 0; m < 4; m++) af[m]  = *reinterpret_cast<const short8*>(&As[wm + m * 16 + fr][fc]);
        #pragma unroll
        for (int n = 0; n < 4; n++) bf8[n] = *reinterpret_cast<const short8*>(&Bs[wn + n * 16 + fr][fc]);
        #pragma unroll
        for (int m = 0; m < 4; m++)
            #pragma unroll
            for (int n = 0; n < 4; n++)
                acc[m][n] = __builtin_amdgcn_mfma_f32_16x16x32_bf16(af[m], bf8[n], acc[m][n], 0, 0, 0);
        __syncthreads();
    }

    const int crow0 = bm0 + wm + (lane >> 4) * 4;
    const int ccol0 = bn0 + wn + fr;
    #pragma unroll
    for (int n = 0; n < 4; n++) {
        const int col = ccol0 + n * 16;
        const float bb = bias[col];
        #pragma unroll
        for (int m = 0; m < 4; m++)
            #pragma unroll
            for (int r = 0; r < 4; r++)
                outp[(size_t)(crow0 + m * 16 + r) * DIM + col] =
                    __float2bfloat16(acc[m][n][r] + bb);
    }
}

// ---------------------------------------------------------------------------
// In-place RMSNorm * g + RoPE. (unchanged, verified)
// ---------------------------------------------------------------------------
__global__ __launch_bounds__(256) void rmsnorm_rope(
    __hip_bfloat16* __restrict__ yq, __hip_bfloat16* __restrict__ yk,
    const float* __restrict__ gq, const float* __restrict__ gk,
    const float* __restrict__ freqs)
{
    const int s = blockIdx.x;
    const int z = blockIdx.y;
    __hip_bfloat16* y = z ? yk : yq;
    const float* g = z ? gk : gq;
    const int t = threadIdx.x;

    float xr[3], xi[3];
    float ss = 0.f;
    #pragma unroll
    for (int i = 0; i < 3; i++) {
        const int p = t + i * 256;
        const unsigned int uu = *reinterpret_cast<const unsigned int*>(&y[(size_t)s * DIM + 2 * p]);
        xr[i] = bf2f((unsigned short)(uu & 0xffffu));
        xi[i] = bf2f((unsigned short)(uu >> 16));
        ss += xr[i] * xr[i] + xi[i] * xi[i];
    }
    #pragma unroll
    for (int m = 1; m < 64; m <<= 1) ss += __shfl_xor(ss, m, 64);
    __shared__ float red[4];
    if ((t & 63) == 0) red[t >> 6] = ss;
    __syncthreads();
    const float sum = red[0] + red[1] + red[2] + red[3];
    const float rs = rsqrtf(sum * (1.0f / DIM) + 1e-6f);
    const int f = s >> 8, hh = (s >> 4) & 15, ww = s & 15;
    const float osc = z ? 1.0f : QSCALE;
    #pragma unroll
    for (int i = 0; i < 3; i++) {
        const int p = t + i * 256;
        const int cc = p & 63;
        const int pos = (cc < 22) ? f : (cc < 43) ? hh : ww;
        const float ang = freqs[pos * 64 + cc];
        float sn, cs;
        sincosf(ang, &sn, &cs);
        const float a = xr[i] * rs * g[2 * p];
        const float b = xi[i] * rs * g[2 * p + 1];
        const unsigned int pk = (unsigned int)f2bf((a * cs - b * sn) * osc)
                              | ((unsigned int)f2bf((a * sn + b * cs) * osc) << 16);
        *reinterpret_cast<unsigned int*>(&y[(size_t)s * DIM + 2 * p]) = pk;
    }
}

// ---------------------------------------------------------------------------
// Transpose V. (unchanged, verified)
// ---------------------------------------------------------------------------
__global__ __launch_bounds__(256) void transpose_v(
    const __hip_bfloat16* __restrict__ vrow,
    __hip_bfloat16* __restrict__ vT)
{
    __shared__ __align__(16) short tile[64][72];
    const int s0 = blockIdx.x * 64;
    const int c0 = blockIdx.y * 64;
    const int t = threadIdx.x;
    #pragma unroll
    for (int i = 0; i < 2; i++) {
        const int ch = t + i * 256;
        const int r = ch >> 3, cc = (ch & 7) * 8;
        *reinterpret_cast<int4*>(&tile[r][cc]) =
            *reinterpret_cast<const int4*>(&vrow[(size_t)(s0 + r) * DIM + c0 + cc]);
    }
    __syncthreads();
    #pragma unroll
    for (int i = 0; i < 2; i++) {
        const int ch = t + i * 256;
        const int c = ch & 63, sc = (ch >> 6) * 8;
        unsigned int w0 = (unsigned short)tile[sc + 0][c] | ((unsigned int)(unsigned short)tile[sc + 1][c] << 16);
        unsigned int w1 = (unsigned short)tile[sc + 2][c] | ((unsigned int)(unsigned short)tile[sc + 3][c] << 16);
        unsigned int w2 = (unsigned short)tile[sc + 4][c] | ((unsigned int)(unsigned short)tile[sc + 5][c] << 16);
        unsigned int w3 = (unsigned short)tile[sc + 6][c] | ((unsigned int)(unsigned short)tile[sc + 7][c] << 16);
        int4 val;
        val.x = (int)w0; val.y = (int)w1; val.z = (int)w2; val.w = (int)w3;
        *reinterpret_cast<int4*>(&vT[(size_t)(c0 + c) * SEQ + s0 + sc]) = val;
    }
}

// ---------------------------------------------------------------------------
// Flash attention v11: full T15 att[2] double-pipeline.
// Iter t: {QK[t+1] -> S_next, PV[t-1] <- Wp} (MFMA, independent) ||
// softmax[t] on S_cur (VALU). K staged 2 ahead (2 slots), V 1 ahead (3 slots).
// S double-state via named saccA/saccB + 2-step unrolled loop (rule #20).
// ---------------------------------------------------------------------------
__global__ __launch_bounds__(256, 2) void flash_attn(
    const __hip_bfloat16* __restrict__ qb,
    const __hip_bfloat16* __restrict__ kb,
    const __hip_bfloat16* __restrict__ vT,
    const int* __restrict__ seq_lens,
    __hip_bfloat16* __restrict__ attno)
{
    __shared__ __align__(16) short Ks[2][64][128];   // 32 KB
    __shared__ __align__(16) short Vs[3][128][64];   // 48 KB
    const int qt = blockIdx.x;
    const int h  = blockIdx.y;
    const int tid = threadIdx.x;
    const int lane = tid & 63;
    const int w = tid >> 6;
    const int q5 = lane & 31;
    const int hi = lane >> 5;
    const int seqlen = seq_lens[0];
    const int swz = (lane & 7) << 4;
    const int NT = SEQ / 64;

    short8 qf[8];
    const int qrow = qt * 128 + w * 32 + q5;
    #pragma unroll
    for (int s = 0; s < 8; s++)
        qf[s] = *reinterpret_cast<const short8*>(&qb[(size_t)qrow * DIM + h * HD + s * 16 + hi * 8]);

    f32x16 oacc[4] = {};
    float m = -1e30f, l = 0.f;
    unsigned int Wp[2][4][2];        // packed P of tile t-1
    f32x16 saccA[2], saccB[2];       // S double-state (named, static idx)

    const int kROW = w * 4 + (lane >> 4);
    const int kCOL = ((lane & 15) ^ (kROW & 7)) * 8;
    const int vROW = w * 8 + (lane >> 3);
    const int vCOL = (((lane & 7) ^ (vROW & 7))) * 8;

    // helpers -----------------------------------------------------------
    auto stageK = [&](int tile, int slot) {
        #pragma unroll
        for (int i = 0; i < 4; i++)
            async_cp16(&Ks[slot][i * 16 + w * 4][0],
                       kb + (size_t)(tile * 64 + i * 16 + kROW) * DIM + h * HD + kCOL);
    };
    auto stageV = [&](int tile, int slot) {
        #pragma unroll
        for (int i = 0; i < 4; i++)
            async_cp16(&Vs[slot][i * 32 + vROW][0],
                       vT + ((size_t)h * HD + i * 32 + vROW) * SEQ + tile * 64 + vCOL);
    };
    auto qk = [&](int slot, f32x16* S) {
        const char* Kp = (const char*)&Ks[slot][0][0];
        S[0] = (f32x16){};
        S[1] = (f32x16){};
        __builtin_amdgcn_s_setprio(1);
        #pragma unroll
        for (int s = 0; s < 8; s++) {
            #pragma unroll
            for (int kbk = 0; kbk < 2; kbk++) {
                short8 kf = *reinterpret_cast<const short8*>(
                    Kp + (kbk * 32 + q5) * 256 + ((s * 32 + hi * 16) ^ swz));
                S[kbk] = __builtin_amdgcn_mfma_f32_32x32x16_bf16(kf, qf[s], S[kbk], 0, 0, 0);
            }
        }
        __builtin_amdgcn_s_setprio(0);
    };
    auto pv = [&](int slot) {
        const char* Vp = (const char*)&Vs[slot][0][0];
        #pragma unroll
        for (int ks = 0; ks < 4; ks++) {
            const int kbk = ks >> 1;
            const int te = (ks & 1) * 2, to = te + 1;
            const int a0 = (int)Wp[kbk][te][0], a1 = (int)Wp[kbk][te][1];
            const int b0 = (int)Wp[kbk][to][0], b1 = (int)Wp[kbk][to][1];
            const int xa0 = __shfl_xor(a0, 32, 64);
            const int xa1 = __shfl_xor(a1, 32, 64);
            const int xb0 = __shfl_xor(b0, 32, 64);
            const int xb1 = __shfl_xor(b1, 32, 64);
            int4 pwv;
            pwv.x = hi ? xb0 : a0;
            pwv.y = hi ? xb1 : a1;
            pwv.z = hi ? b0  : xa0;
            pwv.w = hi ? b1  : xa1;
            const short8 pf = __builtin_bit_cast(short8, pwv);
            __builtin_amdgcn_s_setprio(1);
            #pragma unroll
            for (int cb = 0; cb < 4; cb++) {
                short8 vf = *reinterpret_cast<const short8*>(
                    Vp + (cb * 32 + q5) * 128 + ((ks * 32 + hi * 16) ^ swz));
                oacc[cb] = __builtin_amdgcn_mfma_f32_32x32x16_bf16(vf, pf, oacc[cb], 0, 0, 0);
            }
            __builtin_amdgcn_s_setprio(0);
        }
    };
    auto softmax_step = [&](int tt, f32x16* S) {
        const int kbase = tt * 64;
        float tmax = -1e30f;
        if (kbase + 64 <= seqlen) {
            #pragma unroll
            for (int kbk = 0; kbk < 2; kbk++)
                #pragma unroll
                for (int r = 0; r < 16; r++) tmax = fmaxf(tmax, S[kbk][r]);
        } else {
            #pragma unroll
            for (int kbk = 0; kbk < 2; kbk++)
                #pragma unroll
                for (int r = 0; r < 16; r++) {
                    const int key = kbase + kbk * 32 + (r & 3) + 8 * (r >> 2) + 4 * hi;
                    const float sv = (key < seqlen) ? S[kbk][r] : -1e30f;
                    S[kbk][r] = sv;
                    tmax = fmaxf(tmax, sv);
                }
        }
        tmax = fmaxf(tmax, __shfl_xor(tmax, 32, 64));
        if (!__all(tmax <= m + 8.0f)) {
            const float mn = fmaxf(m, tmax);
            const float alpha = exp2f((m - mn) * LOG2E);
            m = mn;
            l *= alpha;
            #pragma unroll
            for (int cb = 0; cb < 4; cb++)
                #pragma unroll
                for (int r = 0; r < 16; r++) oacc[cb][r] *= alpha;
        }
        float ps = 0.f;
        #pragma unroll
        for (int kbk = 0; kbk < 2; kbk++)
            #pragma unroll
            for (int r = 0; r < 16; r++) {
                const float p = exp2f((S[kbk][r] - m) * LOG2E);
                S[kbk][r] = p;
                ps += p;
            }
        ps += __shfl_xor(ps, 32, 64);
        l += ps;
        #pragma unroll
        for (int kbk = 0; kbk < 2; kbk++)
            #pragma unroll
            for (int tq = 0; tq < 4; tq++) {
                Wp[kbk][tq][0] = (unsigned int)f2bf(S[kbk][4 * tq + 0])
                               | ((unsigned int)f2bf(S[kbk][4 * tq + 1]) << 16);
                Wp[kbk][tq][1] = (unsigned int)f2bf(S[kbk][4 * tq + 2])
                               | ((unsigned int)f2bf(S[kbk][4 * tq + 3]) << 16);
            }
    };
    auto iter_body = [&](int t, f32x16* Scur, f32x16* Snxt) {
        __syncthreads();                 // drains K[t+1], V[t] (issued iter t-1)
        stageV(t + 1, (t + 1) % 3);      // t+1 <= NT-1 always in loop range
        if (t + 2 < NT) stageK(t + 2, t & 1);
        qk((t + 1) & 1, Snxt);           // QK[t+1]
        pv((t - 1) % 3);                 // PV[t-1] from Wp
        softmax_step(t, Scur);           // softmax[t] -> Wp
    };

    // ---- prologue ----
    stageK(0, 0); stageV(0, 0);
    __syncthreads();                     // drain K0,V0
    stageK(1, 1); stageV(1, 1);
    qk(0, saccA);                        // QK[0] (reads K0)
    __syncthreads();                     // drain K1,V1; all waves did QK[0]
    stageK(2, 0);                        // overwrite K0 (safe)
    qk(1, saccB);                        // QK[1]
    softmax_step(0, saccA);              // P[0] -> Wp
    // note: V[1] staged above; iter t=1 stages V[2].

    // ---- main loop: t = 1..NT-2 (62 iters = 31 pairs) ----
    for (int t = 1; t + 1 <= NT - 2; t += 2) {
        iter_body(t,     saccB, saccA);  // softmax[odd] on B, QK[even]->A
        iter_body(t + 1, saccA, saccB);  // softmax[even] on A, QK[odd]->B
    }

    // ---- epilogue: t = NT-1 = 63 ----
    __syncthreads();                     // drains V[63] (staged at t=62)
    pv((NT - 2) % 3);                    // PV[62]
    softmax_step(NT - 1, saccB);         // softmax[63] (S[63] in B) -> Wp
    pv((NT - 1) % 3);                    // PV[63]

    const float inv_l = 1.f / l;
    const size_t obase = (size_t)qrow * DIM + h * HD;
    #pragma unroll
    for (int cb = 0; cb < 4; cb++) {
        #pragma unroll
        for (int tq = 0; tq < 4; tq++) {
            uint2 pko;
            pko.x = (unsigned int)f2bf(oacc[cb][4 * tq + 0] * inv_l)
                  | ((unsigned int)f2bf(oacc[cb][4 * tq + 1] * inv_l) << 16);
            pko.y = (unsigned int)f2bf(oacc[cb][4 * tq + 2] * inv_l)
                  | ((unsigned int)f2bf(oacc[cb][4 * tq + 3] * inv_l) << 16);
            *reinterpret_cast<uint2*>(&attno[obase + cb * 32 + 8 * tq + 4 * hi]) = pko;
        }
    }
}

// ---------------------------------------------------------------------------
// Output GEMM (m97-style staging). (unchanged, verified)
// ---------------------------------------------------------------------------
__global__ __launch_bounds__(256) void gemm_out(
    const __hip_bfloat16* __restrict__ A,
    const __hip_bfloat16* __restrict__ W,
    const float* __restrict__ bias,
    float* __restrict__ outp)
{
    __shared__ __align__(16) short As[128][32];
    __shared__ __align__(16) short Bs[128][32];
    const int bm0 = blockIdx.x * 128;
    const int bn0 = blockIdx.y * 128;
    const int tid = threadIdx.x;
    const int lane = tid & 63;
    const int wid = tid >> 6;
    const int wm = (wid >> 1) * 64;
    const int wn = (wid & 1) * 64;
    const int fr = lane & 15;
    const int fc = (lane >> 4) * 8;
    const int srow = tid >> 2;
    const int scol = (tid & 3) * 8;

    f32x4 acc[4][4] = {};

    for (int kt = 0; kt < DIM; kt += 32) {
        #pragma unroll
        for (int i = 0; i < 2; i++) {
            async_cp16(&As[i * 64 + ((tid >> 6) << 4)][0],
                       A + (size_t)(bm0 + i * 64 + srow) * DIM + kt + scol);
            async_cp16(&Bs[i * 64 + ((tid >> 6) << 4)][0],
                       W + (size_t)(bn0 + i * 64 + srow) * DIM + kt + scol);
        }
        __syncthreads();
        short8 af[4], bf8[4];
        #pragma unroll
        for (int m = 0; m < 4; m++) af[m]  = *reinterpret_cast<const short8*>(&As[wm + m * 16 + fr][fc]);
        #pragma unroll
        for (int n = 0; n < 4; n++) bf8[n] = *reinterpret_cast<const short8*>(&Bs[wn + n * 16 + fr][fc]);
        #pragma unroll
        for (int m = 0; m < 4; m++)
            #pragma unroll
            for (int n = 0; n < 4; n++)
                acc[m][n] = __builtin_amdgcn_mfma_f32_16x16x32_bf16(af[m], bf8[n], acc[m][n], 0, 0, 0);
        __syncthreads();
    }

    const int crow0 = bm0 + wm + (lane >> 4) * 4;
    const int ccol0 = bn0 + wn + fr;
    #pragma unroll
    for (int n = 0; n < 4; n++) {
        const int col = ccol0 + n * 16;
        const float bb = bias[col];
        #pragma unroll
        for (int m = 0; m < 4; m++)
            #pragma unroll
            for (int r = 0; r < 4; r++)
                outp[(size_t)(crow0 + m * 16 + r) * DIM + col] = acc[m][n][r] + bb;
    }
}

// ---------------------------------------------------------------------------
extern "C" void kernel_launch(void* const* d_in, const int* in_sizes, int n_in,
                              void* d_out, int out_size, void* d_ws, size_t ws_size,
                              hipStream_t stream)
{
    const float* x        = (const float*)d_in[0];
    const int*   seq_lens = (const int*)d_in[1];
    const float* freqs    = (const float*)d_in[3];
    const float* wq = (const float*)d_in[4];
    const float* bq = (const float*)d_in[5];
    const float* wk = (const float*)d_in[6];
    const float* bk = (const float*)d_in[7];
    const float* wv = (const float*)d_in[8];
    const float* bv = (const float*)d_in[9];
    const float* wo = (const float*)d_in[10];
    const float* bo = (const float*)d_in[11];
    const float* gq = (const float*)d_in[12];
    const float* gk = (const float*)d_in[13];
    float* out = (float*)d_out;

    // workspace (50,331,648 bytes) + d_out used as early scratch:
    //   yq bf16 [0, 12582912)          (q; dead after flash -> wob aliases)
    //   yk bf16 [12582912, 25165824)
    //   vrow bf16 [25165824, 37748736) (dead after transpose_v; attno aliases)
    //   vT bf16 [37748736, 50331648)   (xb lives here until transpose_v)
    //   wq/wk/wv bf16 -> d_out scratch (until gemm_out writes)
    char* ws = (char*)d_ws;
    __hip_bfloat16* yq    = (__hip_bfloat16*)(ws);
    __hip_bfloat16* yk    = (__hip_bfloat16*)(ws + 12582912);
    __hip_bfloat16* vrow  = (__hip_bfloat16*)(ws + 25165824);
    __hip_bfloat16* vT    = (__hip_bfloat16*)(ws + 37748736);
    __hip_bfloat16* attno = (__hip_bfloat16*)(ws + 25165824);
    __hip_bfloat16* xb    = (__hip_bfloat16*)(ws + 37748736);
    __hip_bfloat16* wob   = (__hip_bfloat16*)(ws);
    __hip_bfloat16* wqb   = (__hip_bfloat16*)d_out;
    __hip_bfloat16* wkb   = wqb + 2359296;
    __hip_bfloat16* wvb   = wkb + 2359296;

    dim3 blk(256);
    convert_bf16<<<dim3(3072), blk, 0, stream>>>(x,  xb,  786432);
    convert_bf16<<<dim3(1152), blk, 0, stream>>>(wq, wqb, 294912);
    convert_bf16<<<dim3(1152), blk, 0, stream>>>(wk, wkb, 294912);
    convert_bf16<<<dim3(1152), blk, 0, stream>>>(wv, wvb, 294912);
    gemm_qkv    <<<dim3(32, 12, 3), blk, 0, stream>>>(xb, wqb, bq, wkb, bk, wvb, bv, yq, yk, vrow);
    rmsnorm_rope<<<dim3(4096, 2),   blk, 0, stream>>>(yq, yk, gq, gk, freqs);
    transpose_v <<<dim3(64, 24),    blk, 0, stream>>>(vrow, vT);
    flash_attn  <<<dim3(32, 12),    blk, 0, stream>>>(yq, yk, vT, seq_lens, attno);
    convert_bf16<<<dim3(1152), blk, 0, stream>>>(wo, wob, 294912);
    gemm_out    <<<dim3(32, 12),    blk, 0, stream>>>(attno, wob, bo, out);
}

// Round 20
// 328.644 us; speedup vs baseline: 1.1118x; 1.0007x over previous
//
#include <hip/hip_runtime.h>
#include <hip/hip_bf16.h>

#define DIM   1536
#define HEADS 12
#define HD    128
#define SEQ   4096
#define QSCALE 0.08838834764831845f
#define LOG2E 1.44269504088896f

typedef __attribute__((ext_vector_type(8))) short short8;
typedef __attribute__((ext_vector_type(4))) float f32x4;
typedef __attribute__((ext_vector_type(16))) float f32x16;

__device__ __forceinline__ unsigned short f2bf(float f) {
    __hip_bfloat16 h = __float2bfloat16(f);
    return *reinterpret_cast<unsigned short*>(&h);
}
__device__ __forceinline__ float bf2f(unsigned short u) {
    return __uint_as_float(((unsigned int)u) << 16);
}
__device__ __forceinline__ void async_cp16(void* lds, const void* g) {
    __builtin_amdgcn_global_load_lds(
        (const __attribute__((address_space(1))) unsigned int*)g,
        (__attribute__((address_space(3))) unsigned int*)lds, 16, 0, 0);
}

// ---------------------------------------------------------------------------
// f32 -> bf16 convert, 8 elements/thread. (single-source variant, for wo)
// ---------------------------------------------------------------------------
__global__ __launch_bounds__(256) void convert_bf16(
    const float* __restrict__ src, __hip_bfloat16* __restrict__ dst, int n8)
{
    const int i = blockIdx.x * 256 + threadIdx.x;
    if (i >= n8) return;
    const float4 a = *reinterpret_cast<const float4*>(src + (size_t)i * 8);
    const float4 b = *reinterpret_cast<const float4*>(src + (size_t)i * 8 + 4);
    uint4 o;
    o.x = (unsigned int)f2bf(a.x) | ((unsigned int)f2bf(a.y) << 16);
    o.y = (unsigned int)f2bf(a.z) | ((unsigned int)f2bf(a.w) << 16);
    o.z = (unsigned int)f2bf(b.x) | ((unsigned int)f2bf(b.y) << 16);
    o.w = (unsigned int)f2bf(b.z) | ((unsigned int)f2bf(b.w) << 16);
    *reinterpret_cast<uint4*>(dst + (size_t)i * 8) = o;
}

// ---------------------------------------------------------------------------
// Batched f32 -> bf16 convert: x, wq, wk, wv in one launch.
// ---------------------------------------------------------------------------
__global__ __launch_bounds__(256) void convert_all(
    const float* __restrict__ x,  const float* __restrict__ wq,
    const float* __restrict__ wk, const float* __restrict__ wv,
    __hip_bfloat16* __restrict__ xb,  __hip_bfloat16* __restrict__ wqb,
    __hip_bfloat16* __restrict__ wkb, __hip_bfloat16* __restrict__ wvb)
{
    const int i = blockIdx.x * 256 + threadIdx.x;   // grid covers 1671168
    const float* src;
    __hip_bfloat16* dst;
    int off;
    if (i < 786432)            { src = x;  dst = xb;  off = i; }
    else if (i < 1081344)      { src = wq; dst = wqb; off = i - 786432; }
    else if (i < 1376256)      { src = wk; dst = wkb; off = i - 1081344; }
    else                       { src = wv; dst = wvb; off = i - 1376256; }
    const float4 a = *reinterpret_cast<const float4*>(src + (size_t)off * 8);
    const float4 b = *reinterpret_cast<const float4*>(src + (size_t)off * 8 + 4);
    uint4 o;
    o.x = (unsigned int)f2bf(a.x) | ((unsigned int)f2bf(a.y) << 16);
    o.y = (unsigned int)f2bf(a.z) | ((unsigned int)f2bf(a.w) << 16);
    o.z = (unsigned int)f2bf(b.x) | ((unsigned int)f2bf(b.y) << 16);
    o.w = (unsigned int)f2bf(b.z) | ((unsigned int)f2bf(b.w) << 16);
    *reinterpret_cast<uint4*>(dst + (size_t)off * 8) = o;
}

// ---------------------------------------------------------------------------
// GEMM (m97-style): y = A(bf16) @ W(bf16)^T + b -> bf16. (unchanged, verified)
// ---------------------------------------------------------------------------
__global__ __launch_bounds__(256) void gemm_qkv(
    const __hip_bfloat16* __restrict__ xb,
    const __hip_bfloat16* __restrict__ wqb, const float* __restrict__ bq,
    const __hip_bfloat16* __restrict__ wkb, const float* __restrict__ bk,
    const __hip_bfloat16* __restrict__ wvb, const float* __restrict__ bv,
    __hip_bfloat16* __restrict__ yq, __hip_bfloat16* __restrict__ yk,
    __hip_bfloat16* __restrict__ vrow)
{
    __shared__ __align__(16) short As[128][32];
    __shared__ __align__(16) short Bs[128][32];
    const int z  = blockIdx.z;
    const __hip_bfloat16* W = (z == 0) ? wqb : (z == 1) ? wkb : wvb;
    const float* bias = (z == 0) ? bq : (z == 1) ? bk : bv;
    __hip_bfloat16* outp = (z == 0) ? yq : (z == 1) ? yk : vrow;
    const int bm0 = blockIdx.x * 128;
    const int bn0 = blockIdx.y * 128;
    const int tid  = threadIdx.x;
    const int lane = tid & 63;
    const int wid  = tid >> 6;
    const int wm = (wid >> 1) * 64;
    const int wn = (wid & 1)  * 64;
    const int fr = lane & 15;
    const int fc = (lane >> 4) * 8;
    const int srow = tid >> 2;
    const int scol = (tid & 3) * 8;

    f32x4 acc[4][4] = {};

    for (int kt = 0; kt < DIM; kt += 32) {
        #pragma unroll
        for (int i = 0; i < 2; i++) {
            async_cp16(&As[i * 64 + ((tid >> 6) << 4)][0],
                       xb + (size_t)(bm0 + i * 64 + srow) * DIM + kt + scol);
            async_cp16(&Bs[i * 64 + ((tid >> 6) << 4)][0],
                       W + (size_t)(bn0 + i * 64 + srow) * DIM + kt + scol);
        }
        __syncthreads();
        short8 af[4], bf8[4];
        #pragma unroll
        for (int m = 0; m < 4; m++) af[m]  = *reinterpret_cast<const short8*>(&As[wm + m * 16 + fr][fc]);
        #pragma unroll
        for (int n = 0; n < 4; n++) bf8[n] = *reinterpret_cast<const short8*>(&Bs[wn + n * 16 + fr][fc]);
        #pragma unroll
        for (int m = 0; m < 4; m++)
            #pragma unroll
            for (int n = 0; n < 4; n++)
                acc[m][n] = __builtin_amdgcn_mfma_f32_16x16x32_bf16(af[m], bf8[n], acc[m][n], 0, 0, 0);
        __syncthreads();
    }

    const int crow0 = bm0 + wm + (lane >> 4) * 4;
    const int ccol0 = bn0 + wn + fr;
    #pragma unroll
    for (int n = 0; n < 4; n++) {
        const int col = ccol0 + n * 16;
        const float bb = bias[col];
        #pragma unroll
        for (int m = 0; m < 4; m++)
            #pragma unroll
            for (int r = 0; r < 4; r++)
                outp[(size_t)(crow0 + m * 16 + r) * DIM + col] =
                    __float2bfloat16(acc[m][n][r] + bb);
    }
}

// ---------------------------------------------------------------------------
// In-place RMSNorm * g + RoPE. (unchanged, verified)
// ---------------------------------------------------------------------------
__global__ __launch_bounds__(256) void rmsnorm_rope(
    __hip_bfloat16* __restrict__ yq, __hip_bfloat16* __restrict__ yk,
    const float* __restrict__ gq, const float* __restrict__ gk,
    const float* __restrict__ freqs)
{
    const int s = blockIdx.x;
    const int z = blockIdx.y;
    __hip_bfloat16* y = z ? yk : yq;
    const float* g = z ? gk : gq;
    const int t = threadIdx.x;

    float xr[3], xi[3];
    float ss = 0.f;
    #pragma unroll
    for (int i = 0; i < 3; i++) {
        const int p = t + i * 256;
        const unsigned int uu = *reinterpret_cast<const unsigned int*>(&y[(size_t)s * DIM + 2 * p]);
        xr[i] = bf2f((unsigned short)(uu & 0xffffu));
        xi[i] = bf2f((unsigned short)(uu >> 16));
        ss += xr[i] * xr[i] + xi[i] * xi[i];
    }
    #pragma unroll
    for (int m = 1; m < 64; m <<= 1) ss += __shfl_xor(ss, m, 64);
    __shared__ float red[4];
    if ((t & 63) == 0) red[t >> 6] = ss;
    __syncthreads();
    const float sum = red[0] + red[1] + red[2] + red[3];
    const float rs = rsqrtf(sum * (1.0f / DIM) + 1e-6f);
    const int f = s >> 8, hh = (s >> 4) & 15, ww = s & 15;
    const float osc = z ? 1.0f : QSCALE;
    #pragma unroll
    for (int i = 0; i < 3; i++) {
        const int p = t + i * 256;
        const int cc = p & 63;
        const int pos = (cc < 22) ? f : (cc < 43) ? hh : ww;
        const float ang = freqs[pos * 64 + cc];
        float sn, cs;
        sincosf(ang, &sn, &cs);
        const float a = xr[i] * rs * g[2 * p];
        const float b = xi[i] * rs * g[2 * p + 1];
        const unsigned int pk = (unsigned int)f2bf((a * cs - b * sn) * osc)
                              | ((unsigned int)f2bf((a * sn + b * cs) * osc) << 16);
        *reinterpret_cast<unsigned int*>(&y[(size_t)s * DIM + 2 * p]) = pk;
    }
}

// ---------------------------------------------------------------------------
// Transpose V. (unchanged, verified)
// ---------------------------------------------------------------------------
__global__ __launch_bounds__(256) void transpose_v(
    const __hip_bfloat16* __restrict__ vrow,
    __hip_bfloat16* __restrict__ vT)
{
    __shared__ __align__(16) short tile[64][72];
    const int s0 = blockIdx.x * 64;
    const int c0 = blockIdx.y * 64;
    const int t = threadIdx.x;
    #pragma unroll
    for (int i = 0; i < 2; i++) {
        const int ch = t + i * 256;
        const int r = ch >> 3, cc = (ch & 7) * 8;
        *reinterpret_cast<int4*>(&tile[r][cc]) =
            *reinterpret_cast<const int4*>(&vrow[(size_t)(s0 + r) * DIM + c0 + cc]);
    }
    __syncthreads();
    #pragma unroll
    for (int i = 0; i < 2; i++) {
        const int ch = t + i * 256;
        const int c = ch & 63, sc = (ch >> 6) * 8;
        unsigned int w0 = (unsigned short)tile[sc + 0][c] | ((unsigned int)(unsigned short)tile[sc + 1][c] << 16);
        unsigned int w1 = (unsigned short)tile[sc + 2][c] | ((unsigned int)(unsigned short)tile[sc + 3][c] << 16);
        unsigned int w2 = (unsigned short)tile[sc + 4][c] | ((unsigned int)(unsigned short)tile[sc + 5][c] << 16);
        unsigned int w3 = (unsigned short)tile[sc + 6][c] | ((unsigned int)(unsigned short)tile[sc + 7][c] << 16);
        int4 val;
        val.x = (int)w0; val.y = (int)w1; val.z = (int)w2; val.w = (int)w3;
        *reinterpret_cast<int4*>(&vT[(size_t)(c0 + c) * SEQ + s0 + sc]) = val;
    }
}

// ---------------------------------------------------------------------------
// Flash attention v12: v10 deferred-PV pipeline (verified, 200us) +
// split QK accumulators (chain depth 8->4) + fma-folded exp2 arg.
// K double-buffered, V triple-buffered (80KB, 2 blocks/CU).
// ---------------------------------------------------------------------------
__global__ __launch_bounds__(256, 2) void flash_attn(
    const __hip_bfloat16* __restrict__ qb,
    const __hip_bfloat16* __restrict__ kb,
    const __hip_bfloat16* __restrict__ vT,
    const int* __restrict__ seq_lens,
    __hip_bfloat16* __restrict__ attno)
{
    __shared__ __align__(16) short Ks[2][64][128];   // 32 KB
    __shared__ __align__(16) short Vs[3][128][64];   // 48 KB
    const int qt = blockIdx.x;
    const int h  = blockIdx.y;
    const int tid = threadIdx.x;
    const int lane = tid & 63;
    const int w = tid >> 6;
    const int q5 = lane & 31;
    const int hi = lane >> 5;
    const int seqlen = seq_lens[0];
    const int swz = (lane & 7) << 4;
    const int NT = SEQ / 64;

    short8 qf[8];
    const int qrow = qt * 128 + w * 32 + q5;
    #pragma unroll
    for (int s = 0; s < 8; s++)
        qf[s] = *reinterpret_cast<const short8*>(&qb[(size_t)qrow * DIM + h * HD + s * 16 + hi * 8]);

    f32x16 oacc[4] = {};
    float m = -1e30f, l = 0.f;
    unsigned int Wp[2][4][2];    // packed P of previous tile (scale m[t-1])

    const int kROW = w * 4 + (lane >> 4);
    const int kCOL = ((lane & 15) ^ (kROW & 7)) * 8;
    const int vROW = w * 8 + (lane >> 3);
    const int vCOL = (((lane & 7) ^ (vROW & 7))) * 8;

    // stage tile 0 (K->buf0, V->slot0)
    #pragma unroll
    for (int i = 0; i < 4; i++) {
        async_cp16(&Ks[0][i * 16 + w * 4][0],
                   kb + (size_t)(i * 16 + kROW) * DIM + h * HD + kCOL);
        async_cp16(&Vs[0][i * 32 + vROW][0],
                   vT + ((size_t)h * HD + i * 32 + vROW) * SEQ + vCOL);
    }
    __syncthreads();

    // ---- peeled iter 0: stage tile1, QK[0], softmax[0] -> Wp (no PV) ----
    {
        #pragma unroll
        for (int i = 0; i < 4; i++) {
            async_cp16(&Ks[1][i * 16 + w * 4][0],
                       kb + (size_t)(64 + i * 16 + kROW) * DIM + h * HD + kCOL);
            async_cp16(&Vs[1][i * 32 + vROW][0],
                       vT + ((size_t)h * HD + i * 32 + vROW) * SEQ + 64 + vCOL);
        }
        const char* Kp = (const char*)&Ks[0][0][0];
        f32x16 sacc[2] = {}, sHi[2] = {};
        __builtin_amdgcn_s_setprio(1);
        #pragma unroll
        for (int s = 0; s < 4; s++)
            #pragma unroll
            for (int kbk = 0; kbk < 2; kbk++) {
                short8 kf = *reinterpret_cast<const short8*>(
                    Kp + (kbk * 32 + q5) * 256 + ((s * 32 + hi * 16) ^ swz));
                sacc[kbk] = __builtin_amdgcn_mfma_f32_32x32x16_bf16(kf, qf[s], sacc[kbk], 0, 0, 0);
            }
        #pragma unroll
        for (int s = 4; s < 8; s++)
            #pragma unroll
            for (int kbk = 0; kbk < 2; kbk++) {
                short8 kf = *reinterpret_cast<const short8*>(
                    Kp + (kbk * 32 + q5) * 256 + ((s * 32 + hi * 16) ^ swz));
                sHi[kbk] = __builtin_amdgcn_mfma_f32_32x32x16_bf16(kf, qf[s], sHi[kbk], 0, 0, 0);
            }
        __builtin_amdgcn_s_setprio(0);
        sacc[0] += sHi[0];
        sacc[1] += sHi[1];
        float tmax = -1e30f;
        #pragma unroll
        for (int kbk = 0; kbk < 2; kbk++)
            #pragma unroll
            for (int r = 0; r < 16; r++) {
                const int key = kbk * 32 + (r & 3) + 8 * (r >> 2) + 4 * hi;
                const float sv = (key < seqlen) ? sacc[kbk][r] : -1e30f;
                sacc[kbk][r] = sv;
                tmax = fmaxf(tmax, sv);
            }
        tmax = fmaxf(tmax, __shfl_xor(tmax, 32, 64));
        m = tmax;
        const float nmL = -m * LOG2E;
        float ps = 0.f;
        #pragma unroll
        for (int kbk = 0; kbk < 2; kbk++)
            #pragma unroll
            for (int r = 0; r < 16; r++) {
                const float p = exp2f(fmaf(sacc[kbk][r], LOG2E, nmL));
                sacc[kbk][r] = p;
                ps += p;
            }
        ps += __shfl_xor(ps, 32, 64);
        l = ps;
        #pragma unroll
        for (int kbk = 0; kbk < 2; kbk++)
            #pragma unroll
            for (int tq = 0; tq < 4; tq++) {
                Wp[kbk][tq][0] = (unsigned int)f2bf(sacc[kbk][4 * tq + 0])
                               | ((unsigned int)f2bf(sacc[kbk][4 * tq + 1]) << 16);
                Wp[kbk][tq][1] = (unsigned int)f2bf(sacc[kbk][4 * tq + 2])
                               | ((unsigned int)f2bf(sacc[kbk][4 * tq + 3]) << 16);
            }
    }

    // ---- main pipeline: t = 1..NT-1 ----
    int vprev = 0, vnext = 2;
    for (int t = 1; t < NT; t++) {
        const int kbase = t * 64;
        __syncthreads();   // stage[t] done; all waves finished iter t-1

        if (t + 1 < NT) {
            const int nb = kbase + 64;
            #pragma unroll
            for (int i = 0; i < 4; i++) {
                async_cp16(&Ks[(t + 1) & 1][i * 16 + w * 4][0],
                           kb + (size_t)(nb + i * 16 + kROW) * DIM + h * HD + kCOL);
                async_cp16(&Vs[vnext][i * 32 + vROW][0],
                           vT + ((size_t)h * HD + i * 32 + vROW) * SEQ + nb + vCOL);
            }
        }

        // QK[t] (split accumulators: 4 independent MFMA chains)
        const char* Kp = (const char*)&Ks[t & 1][0][0];
        f32x16 sacc[2] = {}, sHi[2] = {};
        __builtin_amdgcn_s_setprio(1);
        #pragma unroll
        for (int s = 0; s < 4; s++)
            #pragma unroll
            for (int kbk = 0; kbk < 2; kbk++) {
                short8 kf = *reinterpret_cast<const short8*>(
                    Kp + (kbk * 32 + q5) * 256 + ((s * 32 + hi * 16) ^ swz));
                sacc[kbk] = __builtin_amdgcn_mfma_f32_32x32x16_bf16(kf, qf[s], sacc[kbk], 0, 0, 0);
            }
        #pragma unroll
        for (int s = 4; s < 8; s++)
            #pragma unroll
            for (int kbk = 0; kbk < 2; kbk++) {
                short8 kf = *reinterpret_cast<const short8*>(
                    Kp + (kbk * 32 + q5) * 256 + ((s * 32 + hi * 16) ^ swz));
                sHi[kbk] = __builtin_amdgcn_mfma_f32_32x32x16_bf16(kf, qf[s], sHi[kbk], 0, 0, 0);
            }
        __builtin_amdgcn_s_setprio(0);

        // PV[t-1] (independent of sacc)
        {
            const char* Vp = (const char*)&Vs[vprev][0][0];
            #pragma unroll
            for (int ks = 0; ks < 4; ks++) {
                const int kbk = ks >> 1;
                const int te = (ks & 1) * 2, to = te + 1;
                const int a0 = (int)Wp[kbk][te][0], a1 = (int)Wp[kbk][te][1];
                const int b0 = (int)Wp[kbk][to][0], b1 = (int)Wp[kbk][to][1];
                const int xa0 = __shfl_xor(a0, 32, 64);
                const int xa1 = __shfl_xor(a1, 32, 64);
                const int xb0 = __shfl_xor(b0, 32, 64);
                const int xb1 = __shfl_xor(b1, 32, 64);
                int4 pwv;
                pwv.x = hi ? xb0 : a0;
                pwv.y = hi ? xb1 : a1;
                pwv.z = hi ? b0  : xa0;
                pwv.w = hi ? b1  : xa1;
                const short8 pf = __builtin_bit_cast(short8, pwv);
                __builtin_amdgcn_s_setprio(1);
                #pragma unroll
                for (int cb = 0; cb < 4; cb++) {
                    short8 vf = *reinterpret_cast<const short8*>(
                        Vp + (cb * 32 + q5) * 128 + ((ks * 32 + hi * 16) ^ swz));
                    oacc[cb] = __builtin_amdgcn_mfma_f32_32x32x16_bf16(vf, pf, oacc[cb], 0, 0, 0);
                }
                __builtin_amdgcn_s_setprio(0);
            }
        }

        // softmax[t] (VALU; overlaps MFMA drain)
        sacc[0] += sHi[0];
        sacc[1] += sHi[1];
        float tmax = -1e30f;
        if (kbase + 64 <= seqlen) {
            #pragma unroll
            for (int kbk = 0; kbk < 2; kbk++)
                #pragma unroll
                for (int r = 0; r < 16; r++) tmax = fmaxf(tmax, sacc[kbk][r]);
        } else {
            #pragma unroll
            for (int kbk = 0; kbk < 2; kbk++)
                #pragma unroll
                for (int r = 0; r < 16; r++) {
                    const int key = kbase + kbk * 32 + (r & 3) + 8 * (r >> 2) + 4 * hi;
                    const float sv = (key < seqlen) ? sacc[kbk][r] : -1e30f;
                    sacc[kbk][r] = sv;
                    tmax = fmaxf(tmax, sv);
                }
        }
        tmax = fmaxf(tmax, __shfl_xor(tmax, 32, 64));
        if (!__all(tmax <= m + 8.0f)) {
            const float mn = fmaxf(m, tmax);
            const float alpha = exp2f((m - mn) * LOG2E);
            m = mn;
            l *= alpha;
            #pragma unroll
            for (int cb = 0; cb < 4; cb++)
                #pragma unroll
                for (int r = 0; r < 16; r++) oacc[cb][r] *= alpha;
        }
        const float nmL = -m * LOG2E;
        float ps = 0.f;
        #pragma unroll
        for (int kbk = 0; kbk < 2; kbk++)
            #pragma unroll
            for (int r = 0; r < 16; r++) {
                const float p = exp2f(fmaf(sacc[kbk][r], LOG2E, nmL));
                sacc[kbk][r] = p;
                ps += p;
            }
        ps += __shfl_xor(ps, 32, 64);
        l += ps;
        #pragma unroll
        for (int kbk = 0; kbk < 2; kbk++)
            #pragma unroll
            for (int tq = 0; tq < 4; tq++) {
                Wp[kbk][tq][0] = (unsigned int)f2bf(sacc[kbk][4 * tq + 0])
                               | ((unsigned int)f2bf(sacc[kbk][4 * tq + 1]) << 16);
                Wp[kbk][tq][1] = (unsigned int)f2bf(sacc[kbk][4 * tq + 2])
                               | ((unsigned int)f2bf(sacc[kbk][4 * tq + 3]) << 16);
            }

        vprev = (vprev == 2) ? 0 : vprev + 1;
        vnext = (vnext == 2) ? 0 : vnext + 1;
    }

    // ---- epilogue: PV[NT-1] (V slot = vprev), then divide + store ----
    {
        const char* Vp = (const char*)&Vs[vprev][0][0];
        #pragma unroll
        for (int ks = 0; ks < 4; ks++) {
            const int kbk = ks >> 1;
            const int te = (ks & 1) * 2, to = te + 1;
            const int a0 = (int)Wp[kbk][te][0], a1 = (int)Wp[kbk][te][1];
            const int b0 = (int)Wp[kbk][to][0], b1 = (int)Wp[kbk][to][1];
            const int xa0 = __shfl_xor(a0, 32, 64);
            const int xa1 = __shfl_xor(a1, 32, 64);
            const int xb0 = __shfl_xor(b0, 32, 64);
            const int xb1 = __shfl_xor(b1, 32, 64);
            int4 pwv;
            pwv.x = hi ? xb0 : a0;
            pwv.y = hi ? xb1 : a1;
            pwv.z = hi ? b0  : xa0;
            pwv.w = hi ? b1  : xa1;
            const short8 pf = __builtin_bit_cast(short8, pwv);
            #pragma unroll
            for (int cb = 0; cb < 4; cb++) {
                short8 vf = *reinterpret_cast<const short8*>(
                    Vp + (cb * 32 + q5) * 128 + ((ks * 32 + hi * 16) ^ swz));
                oacc[cb] = __builtin_amdgcn_mfma_f32_32x32x16_bf16(vf, pf, oacc[cb], 0, 0, 0);
            }
        }
    }

    const float inv_l = 1.f / l;
    const size_t obase = (size_t)qrow * DIM + h * HD;
    #pragma unroll
    for (int cb = 0; cb < 4; cb++) {
        #pragma unroll
        for (int tq = 0; tq < 4; tq++) {
            uint2 pko;
            pko.x = (unsigned int)f2bf(oacc[cb][4 * tq + 0] * inv_l)
                  | ((unsigned int)f2bf(oacc[cb][4 * tq + 1] * inv_l) << 16);
            pko.y = (unsigned int)f2bf(oacc[cb][4 * tq + 2] * inv_l)
                  | ((unsigned int)f2bf(oacc[cb][4 * tq + 3] * inv_l) << 16);
            *reinterpret_cast<uint2*>(&attno[obase + cb * 32 + 8 * tq + 4 * hi]) = pko;
        }
    }
}

// ---------------------------------------------------------------------------
// Output GEMM (m97-style staging). (unchanged, verified)
// ---------------------------------------------------------------------------
__global__ __launch_bounds__(256) void gemm_out(
    const __hip_bfloat16* __restrict__ A,
    const __hip_bfloat16* __restrict__ W,
    const float* __restrict__ bias,
    float* __restrict__ outp)
{
    __shared__ __align__(16) short As[128][32];
    __shared__ __align__(16) short Bs[128][32];
    const int bm0 = blockIdx.x * 128;
    const int bn0 = blockIdx.y * 128;
    const int tid = threadIdx.x;
    const int lane = tid & 63;
    const int wid = tid >> 6;
    const int wm = (wid >> 1) * 64;
    const int wn = (wid & 1) * 64;
    const int fr = lane & 15;
    const int fc = (lane >> 4) * 8;
    const int srow = tid >> 2;
    const int scol = (tid & 3) * 8;

    f32x4 acc[4][4] = {};

    for (int kt = 0; kt < DIM; kt += 32) {
        #pragma unroll
        for (int i = 0; i < 2; i++) {
            async_cp16(&As[i * 64 + ((tid >> 6) << 4)][0],
                       A + (size_t)(bm0 + i * 64 + srow) * DIM + kt + scol);
            async_cp16(&Bs[i * 64 + ((tid >> 6) << 4)][0],
                       W + (size_t)(bn0 + i * 64 + srow) * DIM + kt + scol);
        }
        __syncthreads();
        short8 af[4], bf8[4];
        #pragma unroll
        for (int m = 0; m < 4; m++) af[m]  = *reinterpret_cast<const short8*>(&As[wm + m * 16 + fr][fc]);
        #pragma unroll
        for (int n = 0; n < 4; n++) bf8[n] = *reinterpret_cast<const short8*>(&Bs[wn + n * 16 + fr][fc]);
        #pragma unroll
        for (int m = 0; m < 4; m++)
            #pragma unroll
            for (int n = 0; n < 4; n++)
                acc[m][n] = __builtin_amdgcn_mfma_f32_16x16x32_bf16(af[m], bf8[n], acc[m][n], 0, 0, 0);
        __syncthreads();
    }

    const int crow0 = bm0 + wm + (lane >> 4) * 4;
    const int ccol0 = bn0 + wn + fr;
    #pragma unroll
    for (int n = 0; n < 4; n++) {
        const int col = ccol0 + n * 16;
        const float bb = bias[col];
        #pragma unroll
        for (int m = 0; m < 4; m++)
            #pragma unroll
            for (int r = 0; r < 4; r++)
                outp[(size_t)(crow0 + m * 16 + r) * DIM + col] = acc[m][n][r] + bb;
    }
}

// ---------------------------------------------------------------------------
extern "C" void kernel_launch(void* const* d_in, const int* in_sizes, int n_in,
                              void* d_out, int out_size, void* d_ws, size_t ws_size,
                              hipStream_t stream)
{
    const float* x        = (const float*)d_in[0];
    const int*   seq_lens = (const int*)d_in[1];
    const float* freqs    = (const float*)d_in[3];
    const float* wq = (const float*)d_in[4];
    const float* bq = (const float*)d_in[5];
    const float* wk = (const float*)d_in[6];
    const float* bk = (const float*)d_in[7];
    const float* wv = (const float*)d_in[8];
    const float* bv = (const float*)d_in[9];
    const float* wo = (const float*)d_in[10];
    const float* bo = (const float*)d_in[11];
    const float* gq = (const float*)d_in[12];
    const float* gk = (const float*)d_in[13];
    float* out = (float*)d_out;

    // workspace (50,331,648 bytes) + d_out used as early scratch:
    //   yq bf16 [0, 12582912)          (q; dead after flash -> wob aliases)
    //   yk bf16 [12582912, 25165824)
    //   vrow bf16 [25165824, 37748736) (dead after transpose_v; attno aliases)
    //   vT bf16 [37748736, 50331648)   (xb lives here until transpose_v)
    //   wq/wk/wv bf16 -> d_out scratch (until gemm_out writes)
    char* ws = (char*)d_ws;
    __hip_bfloat16* yq    = (__hip_bfloat16*)(ws);
    __hip_bfloat16* yk    = (__hip_bfloat16*)(ws + 12582912);
    __hip_bfloat16* vrow  = (__hip_bfloat16*)(ws + 25165824);
    __hip_bfloat16* vT    = (__hip_bfloat16*)(ws + 37748736);
    __hip_bfloat16* attno = (__hip_bfloat16*)(ws + 25165824);
    __hip_bfloat16* xb    = (__hip_bfloat16*)(ws + 37748736);
    __hip_bfloat16* wob   = (__hip_bfloat16*)(ws);
    __hip_bfloat16* wqb   = (__hip_bfloat16*)d_out;
    __hip_bfloat16* wkb   = wqb + 2359296;
    __hip_bfloat16* wvb   = wkb + 2359296;

    dim3 blk(256);
    convert_all <<<dim3(6528), blk, 0, stream>>>(x, wq, wk, wv, xb, wqb, wkb, wvb);
    gemm_qkv    <<<dim3(32, 12, 3), blk, 0, stream>>>(xb, wqb, bq, wkb, bk, wvb, bv, yq, yk, vrow);
    rmsnorm_rope<<<dim3(4096, 2),   blk, 0, stream>>>(yq, yk, gq, gk, freqs);
    transpose_v <<<dim3(64, 24),    blk, 0, stream>>>(vrow, vT);
    flash_attn  <<<dim3(32, 12),    blk, 0, stream>>>(yq, yk, vT, seq_lens, attno);
    convert_bf16<<<dim3(1152), blk, 0, stream>>>(wo, wob, 294912);
    gemm_out    <<<dim3(32, 12),    blk, 0, stream>>>(attno, wob, bo, out);
}

// Round 21
// 323.960 us; speedup vs baseline: 1.1279x; 1.0145x over previous
//
#include <hip/hip_runtime.h>
#include <hip/hip_bf16.h>

#define DIM   1536
#define HEADS 12
#define HD    128
#define SEQ   4096
#define QSCALE 0.08838834764831845f
#define LOG2E 1.44269504088896f

typedef __attribute__((ext_vector_type(8))) short short8;
typedef __attribute__((ext_vector_type(4))) float f32x4;
typedef __attribute__((ext_vector_type(16))) float f32x16;

__device__ __forceinline__ unsigned short f2bf(float f) {
    __hip_bfloat16 h = __float2bfloat16(f);
    return *reinterpret_cast<unsigned short*>(&h);
}
__device__ __forceinline__ float bf2f(unsigned short u) {
    return __uint_as_float(((unsigned int)u) << 16);
}
__device__ __forceinline__ void async_cp16(void* lds, const void* g) {
    __builtin_amdgcn_global_load_lds(
        (const __attribute__((address_space(1))) unsigned int*)g,
        (__attribute__((address_space(3))) unsigned int*)lds, 16, 0, 0);
}

// ---------------------------------------------------------------------------
// f32 -> bf16 convert, 8 elements/thread. (for wo, post-flash)
// ---------------------------------------------------------------------------
__global__ __launch_bounds__(256) void convert_bf16(
    const float* __restrict__ src, __hip_bfloat16* __restrict__ dst, int n8)
{
    const int i = blockIdx.x * 256 + threadIdx.x;
    if (i >= n8) return;
    const float4 a = *reinterpret_cast<const float4*>(src + (size_t)i * 8);
    const float4 b = *reinterpret_cast<const float4*>(src + (size_t)i * 8 + 4);
    uint4 o;
    o.x = (unsigned int)f2bf(a.x) | ((unsigned int)f2bf(a.y) << 16);
    o.y = (unsigned int)f2bf(a.z) | ((unsigned int)f2bf(a.w) << 16);
    o.z = (unsigned int)f2bf(b.x) | ((unsigned int)f2bf(b.y) << 16);
    o.w = (unsigned int)f2bf(b.z) | ((unsigned int)f2bf(b.w) << 16);
    *reinterpret_cast<uint4*>(dst + (size_t)i * 8) = o;
}

// ---------------------------------------------------------------------------
// Batched f32 -> bf16 convert: x, wq, wk, wv in one launch. (verified r20)
// ---------------------------------------------------------------------------
__global__ __launch_bounds__(256) void convert_all(
    const float* __restrict__ x,  const float* __restrict__ wq,
    const float* __restrict__ wk, const float* __restrict__ wv,
    __hip_bfloat16* __restrict__ xb,  __hip_bfloat16* __restrict__ wqb,
    __hip_bfloat16* __restrict__ wkb, __hip_bfloat16* __restrict__ wvb)
{
    const int i = blockIdx.x * 256 + threadIdx.x;   // grid covers 1671168
    const float* src;
    __hip_bfloat16* dst;
    int off;
    if (i < 786432)            { src = x;  dst = xb;  off = i; }
    else if (i < 1081344)      { src = wq; dst = wqb; off = i - 786432; }
    else if (i < 1376256)      { src = wk; dst = wkb; off = i - 1081344; }
    else                       { src = wv; dst = wvb; off = i - 1376256; }
    const float4 a = *reinterpret_cast<const float4*>(src + (size_t)off * 8);
    const float4 b = *reinterpret_cast<const float4*>(src + (size_t)off * 8 + 4);
    uint4 o;
    o.x = (unsigned int)f2bf(a.x) | ((unsigned int)f2bf(a.y) << 16);
    o.y = (unsigned int)f2bf(a.z) | ((unsigned int)f2bf(a.w) << 16);
    o.z = (unsigned int)f2bf(b.x) | ((unsigned int)f2bf(b.y) << 16);
    o.w = (unsigned int)f2bf(b.z) | ((unsigned int)f2bf(b.w) << 16);
    *reinterpret_cast<uint4*>(dst + (size_t)off * 8) = o;
}

// ---------------------------------------------------------------------------
// GEMM (m97-style): y = A(bf16) @ W(bf16)^T + b -> bf16. (unchanged, verified)
// ---------------------------------------------------------------------------
__global__ __launch_bounds__(256) void gemm_qkv(
    const __hip_bfloat16* __restrict__ xb,
    const __hip_bfloat16* __restrict__ wqb, const float* __restrict__ bq,
    const __hip_bfloat16* __restrict__ wkb, const float* __restrict__ bk,
    const __hip_bfloat16* __restrict__ wvb, const float* __restrict__ bv,
    __hip_bfloat16* __restrict__ yq, __hip_bfloat16* __restrict__ yk,
    __hip_bfloat16* __restrict__ vrow)
{
    __shared__ __align__(16) short As[128][32];
    __shared__ __align__(16) short Bs[128][32];
    const int z  = blockIdx.z;
    const __hip_bfloat16* W = (z == 0) ? wqb : (z == 1) ? wkb : wvb;
    const float* bias = (z == 0) ? bq : (z == 1) ? bk : bv;
    __hip_bfloat16* outp = (z == 0) ? yq : (z == 1) ? yk : vrow;
    const int bm0 = blockIdx.x * 128;
    const int bn0 = blockIdx.y * 128;
    const int tid  = threadIdx.x;
    const int lane = tid & 63;
    const int wid  = tid >> 6;
    const int wm = (wid >> 1) * 64;
    const int wn = (wid & 1)  * 64;
    const int fr = lane & 15;
    const int fc = (lane >> 4) * 8;
    const int srow = tid >> 2;
    const int scol = (tid & 3) * 8;

    f32x4 acc[4][4] = {};

    for (int kt = 0; kt < DIM; kt += 32) {
        #pragma unroll
        for (int i = 0; i < 2; i++) {
            async_cp16(&As[i * 64 + ((tid >> 6) << 4)][0],
                       xb + (size_t)(bm0 + i * 64 + srow) * DIM + kt + scol);
            async_cp16(&Bs[i * 64 + ((tid >> 6) << 4)][0],
                       W + (size_t)(bn0 + i * 64 + srow) * DIM + kt + scol);
        }
        __syncthreads();
        short8 af[4], bf8[4];
        #pragma unroll
        for (int m = 0; m < 4; m++) af[m]  = *reinterpret_cast<const short8*>(&As[wm + m * 16 + fr][fc]);
        #pragma unroll
        for (int n = 0; n < 4; n++) bf8[n] = *reinterpret_cast<const short8*>(&Bs[wn + n * 16 + fr][fc]);
        #pragma unroll
        for (int m = 0; m < 4; m++)
            #pragma unroll
            for (int n = 0; n < 4; n++)
                acc[m][n] = __builtin_amdgcn_mfma_f32_16x16x32_bf16(af[m], bf8[n], acc[m][n], 0, 0, 0);
        __syncthreads();
    }

    const int crow0 = bm0 + wm + (lane >> 4) * 4;
    const int ccol0 = bn0 + wn + fr;
    #pragma unroll
    for (int n = 0; n < 4; n++) {
        const int col = ccol0 + n * 16;
        const float bb = bias[col];
        #pragma unroll
        for (int m = 0; m < 4; m++)
            #pragma unroll
            for (int r = 0; r < 4; r++)
                outp[(size_t)(crow0 + m * 16 + r) * DIM + col] =
                    __float2bfloat16(acc[m][n][r] + bb);
    }
}

// ---------------------------------------------------------------------------
// Merged: RMSNorm+RoPE (blocks 0..8191) and V-transpose (blocks 8192..9727).
// Both consume gemm_qkv outputs; block-uniform branch.
// ---------------------------------------------------------------------------
__global__ __launch_bounds__(256) void norm_rope_transpose(
    __hip_bfloat16* __restrict__ yq, __hip_bfloat16* __restrict__ yk,
    const float* __restrict__ gq, const float* __restrict__ gk,
    const float* __restrict__ freqs,
    const __hip_bfloat16* __restrict__ vrow, __hip_bfloat16* __restrict__ vT)
{
    __shared__ float red[4];
    __shared__ __align__(16) short tile[64][72];
    const int b = blockIdx.x;
    const int t = threadIdx.x;

    if (b < 8192) {
        const int s = b >> 1;
        const int z = b & 1;
        __hip_bfloat16* y = z ? yk : yq;
        const float* g = z ? gk : gq;

        float xr[3], xi[3];
        float ss = 0.f;
        #pragma unroll
        for (int i = 0; i < 3; i++) {
            const int p = t + i * 256;
            const unsigned int uu = *reinterpret_cast<const unsigned int*>(&y[(size_t)s * DIM + 2 * p]);
            xr[i] = bf2f((unsigned short)(uu & 0xffffu));
            xi[i] = bf2f((unsigned short)(uu >> 16));
            ss += xr[i] * xr[i] + xi[i] * xi[i];
        }
        #pragma unroll
        for (int m = 1; m < 64; m <<= 1) ss += __shfl_xor(ss, m, 64);
        if ((t & 63) == 0) red[t >> 6] = ss;
        __syncthreads();
        const float sum = red[0] + red[1] + red[2] + red[3];
        const float rs = rsqrtf(sum * (1.0f / DIM) + 1e-6f);
        const int f = s >> 8, hh = (s >> 4) & 15, ww = s & 15;
        const float osc = z ? 1.0f : QSCALE;
        #pragma unroll
        for (int i = 0; i < 3; i++) {
            const int p = t + i * 256;
            const int cc = p & 63;
            const int pos = (cc < 22) ? f : (cc < 43) ? hh : ww;
            const float ang = freqs[pos * 64 + cc];
            float sn, cs;
            sincosf(ang, &sn, &cs);
            const float a = xr[i] * rs * g[2 * p];
            const float bb = xi[i] * rs * g[2 * p + 1];
            const unsigned int pk = (unsigned int)f2bf((a * cs - bb * sn) * osc)
                                  | ((unsigned int)f2bf((a * sn + bb * cs) * osc) << 16);
            *reinterpret_cast<unsigned int*>(&y[(size_t)s * DIM + 2 * p]) = pk;
        }
    } else {
        const int tb = b - 8192;
        const int s0 = (tb & 63) * 64;
        const int c0 = (tb >> 6) * 64;
        #pragma unroll
        for (int i = 0; i < 2; i++) {
            const int ch = t + i * 256;
            const int r = ch >> 3, cc = (ch & 7) * 8;
            *reinterpret_cast<int4*>(&tile[r][cc]) =
                *reinterpret_cast<const int4*>(&vrow[(size_t)(s0 + r) * DIM + c0 + cc]);
        }
        __syncthreads();
        #pragma unroll
        for (int i = 0; i < 2; i++) {
            const int ch = t + i * 256;
            const int c = ch & 63, sc = (ch >> 6) * 8;
            unsigned int w0 = (unsigned short)tile[sc + 0][c] | ((unsigned int)(unsigned short)tile[sc + 1][c] << 16);
            unsigned int w1 = (unsigned short)tile[sc + 2][c] | ((unsigned int)(unsigned short)tile[sc + 3][c] << 16);
            unsigned int w2 = (unsigned short)tile[sc + 4][c] | ((unsigned int)(unsigned short)tile[sc + 5][c] << 16);
            unsigned int w3 = (unsigned short)tile[sc + 6][c] | ((unsigned int)(unsigned short)tile[sc + 7][c] << 16);
            int4 val;
            val.x = (int)w0; val.y = (int)w1; val.z = (int)w2; val.w = (int)w3;
            *reinterpret_cast<int4*>(&vT[(size_t)(c0 + c) * SEQ + s0 + sc]) = val;
        }
    }
}

// ---------------------------------------------------------------------------
// Flash attention v13: v10 deferred-PV pipeline + pre-gathered P fragments
// (PV = pure register MFMA cluster) + tree max/sum reductions.
// K double-buffered, V triple-buffered (80KB, 2 blocks/CU).
// ---------------------------------------------------------------------------
__global__ __launch_bounds__(256, 2) void flash_attn(
    const __hip_bfloat16* __restrict__ qb,
    const __hip_bfloat16* __restrict__ kb,
    const __hip_bfloat16* __restrict__ vT,
    const int* __restrict__ seq_lens,
    __hip_bfloat16* __restrict__ attno)
{
    __shared__ __align__(16) short Ks[2][64][128];   // 32 KB
    __shared__ __align__(16) short Vs[3][128][64];   // 48 KB
    const int qt = blockIdx.x;
    const int h  = blockIdx.y;
    const int tid = threadIdx.x;
    const int lane = tid & 63;
    const int w = tid >> 6;
    const int q5 = lane & 31;
    const int hi = lane >> 5;
    const int seqlen = seq_lens[0];
    const int swz = (lane & 7) << 4;
    const int NT = SEQ / 64;

    short8 qf[8];
    const int qrow = qt * 128 + w * 32 + q5;
    #pragma unroll
    for (int s = 0; s < 8; s++)
        qf[s] = *reinterpret_cast<const short8*>(&qb[(size_t)qrow * DIM + h * HD + s * 16 + hi * 8]);

    f32x16 oacc[4] = {};
    float m = -1e30f, l = 0.f;
    unsigned int WpG[4][4];      // pre-gathered PV B-fragments of tile t-1

    const int kROW = w * 4 + (lane >> 4);
    const int kCOL = ((lane & 15) ^ (kROW & 7)) * 8;
    const int vROW = w * 8 + (lane >> 3);
    const int vCOL = (((lane & 7) ^ (vROW & 7))) * 8;

    auto stageK = [&](int tile, int slot) {
        #pragma unroll
        for (int i = 0; i < 4; i++)
            async_cp16(&Ks[slot][i * 16 + w * 4][0],
                       kb + (size_t)(tile * 64 + i * 16 + kROW) * DIM + h * HD + kCOL);
    };
    auto stageV = [&](int tile, int slot) {
        #pragma unroll
        for (int i = 0; i < 4; i++)
            async_cp16(&Vs[slot][i * 32 + vROW][0],
                       vT + ((size_t)h * HD + i * 32 + vROW) * SEQ + tile * 64 + vCOL);
    };
    // PV: pure register MFMA cluster (fragments pre-gathered in WpG)
    auto pv = [&](int slot) {
        const char* Vp = (const char*)&Vs[slot][0][0];
        __builtin_amdgcn_s_setprio(1);
        #pragma unroll
        for (int ks = 0; ks < 4; ks++) {
            int4 pwv;
            pwv.x = (int)WpG[ks][0];
            pwv.y = (int)WpG[ks][1];
            pwv.z = (int)WpG[ks][2];
            pwv.w = (int)WpG[ks][3];
            const short8 pf = __builtin_bit_cast(short8, pwv);
            #pragma unroll
            for (int cb = 0; cb < 4; cb++) {
                short8 vf = *reinterpret_cast<const short8*>(
                    Vp + (cb * 32 + q5) * 128 + ((ks * 32 + hi * 16) ^ swz));
                oacc[cb] = __builtin_amdgcn_mfma_f32_32x32x16_bf16(vf, pf, oacc[cb], 0, 0, 0);
            }
        }
        __builtin_amdgcn_s_setprio(0);
    };
    // softmax + pack + gather -> WpG (tree reductions)
    auto softmax_pack = [&](int tt, f32x16* S) {
        const int kbase = tt * 64;
        float v[32];
        if (kbase + 64 <= seqlen) {
            #pragma unroll
            for (int kbk = 0; kbk < 2; kbk++)
                #pragma unroll
                for (int r = 0; r < 16; r++) v[kbk * 16 + r] = S[kbk][r];
        } else {
            #pragma unroll
            for (int kbk = 0; kbk < 2; kbk++)
                #pragma unroll
                for (int r = 0; r < 16; r++) {
                    const int key = kbase + kbk * 32 + (r & 3) + 8 * (r >> 2) + 4 * hi;
                    const float sv = (key < seqlen) ? S[kbk][r] : -1e30f;
                    S[kbk][r] = sv;
                    v[kbk * 16 + r] = sv;
                }
        }
        #pragma unroll
        for (int st = 16; st >= 1; st >>= 1)
            #pragma unroll
            for (int i = 0; i < st; i++) v[i] = fmaxf(v[i], v[i + st]);
        float tmax = fmaxf(v[0], __shfl_xor(v[0], 32, 64));

        if (!__all(tmax <= m + 8.0f)) {
            const float mn = fmaxf(m, tmax);
            const float alpha = exp2f((m - mn) * LOG2E);
            m = mn;
            l *= alpha;
            #pragma unroll
            for (int cb = 0; cb < 4; cb++)
                #pragma unroll
                for (int r = 0; r < 16; r++) oacc[cb][r] *= alpha;
        }
        const float nmL = -m * LOG2E;
        #pragma unroll
        for (int kbk = 0; kbk < 2; kbk++)
            #pragma unroll
            for (int r = 0; r < 16; r++) {
                const float p = exp2f(fmaf(S[kbk][r], LOG2E, nmL));
                S[kbk][r] = p;
                v[kbk * 16 + r] = p;
            }
        #pragma unroll
        for (int st = 16; st >= 1; st >>= 1)
            #pragma unroll
            for (int i = 0; i < st; i++) v[i] += v[i + st];
        l += v[0] + __shfl_xor(v[0], 32, 64);

        unsigned int Wl[2][4][2];
        #pragma unroll
        for (int kbk = 0; kbk < 2; kbk++)
            #pragma unroll
            for (int tq = 0; tq < 4; tq++) {
                Wl[kbk][tq][0] = (unsigned int)f2bf(S[kbk][4 * tq + 0])
                               | ((unsigned int)f2bf(S[kbk][4 * tq + 1]) << 16);
                Wl[kbk][tq][1] = (unsigned int)f2bf(S[kbk][4 * tq + 2])
                               | ((unsigned int)f2bf(S[kbk][4 * tq + 3]) << 16);
            }
        #pragma unroll
        for (int ks = 0; ks < 4; ks++) {
            const int kbk = ks >> 1;
            const int te = (ks & 1) * 2, to = te + 1;
            const int a0 = (int)Wl[kbk][te][0], a1 = (int)Wl[kbk][te][1];
            const int b0 = (int)Wl[kbk][to][0], b1 = (int)Wl[kbk][to][1];
            const int xa0 = __shfl_xor(a0, 32, 64);
            const int xa1 = __shfl_xor(a1, 32, 64);
            const int xb0 = __shfl_xor(b0, 32, 64);
            const int xb1 = __shfl_xor(b1, 32, 64);
            WpG[ks][0] = (unsigned int)(hi ? xb0 : a0);
            WpG[ks][1] = (unsigned int)(hi ? xb1 : a1);
            WpG[ks][2] = (unsigned int)(hi ? b0  : xa0);
            WpG[ks][3] = (unsigned int)(hi ? b1  : xa1);
        }
    };
    auto qk = [&](int slot, f32x16* S) {
        const char* Kp = (const char*)&Ks[slot][0][0];
        __builtin_amdgcn_s_setprio(1);
        #pragma unroll
        for (int s = 0; s < 8; s++)
            #pragma unroll
            for (int kbk = 0; kbk < 2; kbk++) {
                short8 kf = *reinterpret_cast<const short8*>(
                    Kp + (kbk * 32 + q5) * 256 + ((s * 32 + hi * 16) ^ swz));
                S[kbk] = __builtin_amdgcn_mfma_f32_32x32x16_bf16(kf, qf[s], S[kbk], 0, 0, 0);
            }
        __builtin_amdgcn_s_setprio(0);
    };

    // ---- prologue: stage 0, QK[0], softmax[0] (general path: alpha=0) ----
    stageK(0, 0); stageV(0, 0);
    __syncthreads();
    stageK(1, 1); stageV(1, 1);
    {
        f32x16 sacc[2] = {};
        qk(0, sacc);
        softmax_pack(0, sacc);
    }

    // ---- main pipeline: t = 1..NT-1 ----
    int vprev = 0, vnext = 2;
    for (int t = 1; t < NT; t++) {
        __syncthreads();   // drains stage[t]; all waves finished iter t-1
        if (t + 1 < NT) {
            stageK(t + 1, (t + 1) & 1);
            stageV(t + 1, vnext);
        }
        f32x16 sacc[2] = {};
        qk(t & 1, sacc);          // QK[t]
        pv(vprev);                // PV[t-1], pure MFMA
        softmax_pack(t, sacc);    // softmax[t] -> WpG
        vprev = (vprev == 2) ? 0 : vprev + 1;
        vnext = (vnext == 2) ? 0 : vnext + 1;
    }

    // ---- epilogue: PV[NT-1], divide, store ----
    pv(vprev);

    const float inv_l = 1.f / l;
    const size_t obase = (size_t)qrow * DIM + h * HD;
    #pragma unroll
    for (int cb = 0; cb < 4; cb++) {
        #pragma unroll
        for (int tq = 0; tq < 4; tq++) {
            uint2 pko;
            pko.x = (unsigned int)f2bf(oacc[cb][4 * tq + 0] * inv_l)
                  | ((unsigned int)f2bf(oacc[cb][4 * tq + 1] * inv_l) << 16);
            pko.y = (unsigned int)f2bf(oacc[cb][4 * tq + 2] * inv_l)
                  | ((unsigned int)f2bf(oacc[cb][4 * tq + 3] * inv_l) << 16);
            *reinterpret_cast<uint2*>(&attno[obase + cb * 32 + 8 * tq + 4 * hi]) = pko;
        }
    }
}

// ---------------------------------------------------------------------------
// Output GEMM (m97-style staging). (unchanged, verified)
// ---------------------------------------------------------------------------
__global__ __launch_bounds__(256) void gemm_out(
    const __hip_bfloat16* __restrict__ A,
    const __hip_bfloat16* __restrict__ W,
    const float* __restrict__ bias,
    float* __restrict__ outp)
{
    __shared__ __align__(16) short As[128][32];
    __shared__ __align__(16) short Bs[128][32];
    const int bm0 = blockIdx.x * 128;
    const int bn0 = blockIdx.y * 128;
    const int tid = threadIdx.x;
    const int lane = tid & 63;
    const int wid = tid >> 6;
    const int wm = (wid >> 1) * 64;
    const int wn = (wid & 1) * 64;
    const int fr = lane & 15;
    const int fc = (lane >> 4) * 8;
    const int srow = tid >> 2;
    const int scol = (tid & 3) * 8;

    f32x4 acc[4][4] = {};

    for (int kt = 0; kt < DIM; kt += 32) {
        #pragma unroll
        for (int i = 0; i < 2; i++) {
            async_cp16(&As[i * 64 + ((tid >> 6) << 4)][0],
                       A + (size_t)(bm0 + i * 64 + srow) * DIM + kt + scol);
            async_cp16(&Bs[i * 64 + ((tid >> 6) << 4)][0],
                       W + (size_t)(bn0 + i * 64 + srow) * DIM + kt + scol);
        }
        __syncthreads();
        short8 af[4], bf8[4];
        #pragma unroll
        for (int m = 0; m < 4; m++) af[m]  = *reinterpret_cast<const short8*>(&As[wm + m * 16 + fr][fc]);
        #pragma unroll
        for (int n = 0; n < 4; n++) bf8[n] = *reinterpret_cast<const short8*>(&Bs[wn + n * 16 + fr][fc]);
        #pragma unroll
        for (int m = 0; m < 4; m++)
            #pragma unroll
            for (int n = 0; n < 4; n++)
                acc[m][n] = __builtin_amdgcn_mfma_f32_16x16x32_bf16(af[m], bf8[n], acc[m][n], 0, 0, 0);
        __syncthreads();
    }

    const int crow0 = bm0 + wm + (lane >> 4) * 4;
    const int ccol0 = bn0 + wn + fr;
    #pragma unroll
    for (int n = 0; n < 4; n++) {
        const int col = ccol0 + n * 16;
        const float bb = bias[col];
        #pragma unroll
        for (int m = 0; m < 4; m++)
            #pragma unroll
            for (int r = 0; r < 4; r++)
                outp[(size_t)(crow0 + m * 16 + r) * DIM + col] = acc[m][n][r] + bb;
    }
}

// ---------------------------------------------------------------------------
extern "C" void kernel_launch(void* const* d_in, const int* in_sizes, int n_in,
                              void* d_out, int out_size, void* d_ws, size_t ws_size,
                              hipStream_t stream)
{
    const float* x        = (const float*)d_in[0];
    const int*   seq_lens = (const int*)d_in[1];
    const float* freqs    = (const float*)d_in[3];
    const float* wq = (const float*)d_in[4];
    const float* bq = (const float*)d_in[5];
    const float* wk = (const float*)d_in[6];
    const float* bk = (const float*)d_in[7];
    const float* wv = (const float*)d_in[8];
    const float* bv = (const float*)d_in[9];
    const float* wo = (const float*)d_in[10];
    const float* bo = (const float*)d_in[11];
    const float* gq = (const float*)d_in[12];
    const float* gk = (const float*)d_in[13];
    float* out = (float*)d_out;

    // workspace (50,331,648 bytes) + d_out used as early scratch:
    //   yq bf16 [0, 12582912)          (q; dead after flash -> wob aliases)
    //   yk bf16 [12582912, 25165824)
    //   vrow bf16 [25165824, 37748736) (dead after transpose; attno aliases)
    //   vT bf16 [37748736, 50331648)   (xb lives here until transpose)
    //   wq/wk/wv bf16 -> d_out scratch (until gemm_out writes)
    char* ws = (char*)d_ws;
    __hip_bfloat16* yq    = (__hip_bfloat16*)(ws);
    __hip_bfloat16* yk    = (__hip_bfloat16*)(ws + 12582912);
    __hip_bfloat16* vrow  = (__hip_bfloat16*)(ws + 25165824);
    __hip_bfloat16* vT    = (__hip_bfloat16*)(ws + 37748736);
    __hip_bfloat16* attno = (__hip_bfloat16*)(ws + 25165824);
    __hip_bfloat16* xb    = (__hip_bfloat16*)(ws + 37748736);
    __hip_bfloat16* wob   = (__hip_bfloat16*)(ws);
    __hip_bfloat16* wqb   = (__hip_bfloat16*)d_out;
    __hip_bfloat16* wkb   = wqb + 2359296;
    __hip_bfloat16* wvb   = wkb + 2359296;

    dim3 blk(256);
    convert_all        <<<dim3(6528), blk, 0, stream>>>(x, wq, wk, wv, xb, wqb, wkb, wvb);
    gemm_qkv           <<<dim3(32, 12, 3), blk, 0, stream>>>(xb, wqb, bq, wkb, bk, wvb, bv, yq, yk, vrow);
    norm_rope_transpose<<<dim3(9728), blk, 0, stream>>>(yq, yk, gq, gk, freqs, vrow, vT);
    flash_attn         <<<dim3(32, 12), blk, 0, stream>>>(yq, yk, vT, seq_lens, attno);
    convert_bf16       <<<dim3(1152), blk, 0, stream>>>(wo, wob, 294912);
    gemm_out           <<<dim3(32, 12), blk, 0, stream>>>(attno, wob, bo, out);
}